// Round 1
// baseline (4428.783 us; speedup 1.0000x reference)
//
#include <hip/hip_runtime.h>
#include <math.h>

#define N_NODES 50000
#define N_EDGES 800000
#define IN_DIM 128
#define HID 256
#define NCLASS 40

// ---------------- init: y = bufA = 0.5*feats; bufB = 0 ----------------
__global__ void init_kernel(const float* __restrict__ feats,
                            float* __restrict__ y,
                            float* __restrict__ bufA,
                            float* __restrict__ bufB) {
    int i = blockIdx.x * blockDim.x + threadIdx.x;   // float4 index
    const float4* f4 = (const float4*)feats;
    float4 v = f4[i];
    v.x *= 0.5f; v.y *= 0.5f; v.z *= 0.5f; v.w *= 0.5f;
    ((float4*)y)[i] = v;
    ((float4*)bufA)[i] = v;
    ((float4*)bufB)[i] = make_float4(0.f, 0.f, 0.f, 0.f);
}

// ---------------- spmm: Hout[row] += val * Hin[col]  (atomic) ----------------
// 32 threads per edge, each handles 4 contiguous dims (float4 gather, 4 atomics)
__global__ void spmm_atomic(const int* __restrict__ rows,
                            const int* __restrict__ cols,
                            const float* __restrict__ vals,
                            const float* __restrict__ Hin,
                            float* __restrict__ Hout) {
    int t = blockIdx.x * blockDim.x + threadIdx.x;
    int e = t >> 5;
    if (e >= N_EDGES) return;
    int d4 = (t & 31) << 2;
    int r = rows[e];
    int c = cols[e];
    float v = vals[e];
    float4 h = *(const float4*)(Hin + c * IN_DIM + d4);
    float* o = Hout + r * IN_DIM + d4;
    atomicAdd(o + 0, v * h.x);
    atomicAdd(o + 1, v * h.y);
    atomicAdd(o + 2, v * h.z);
    atomicAdd(o + 3, v * h.w);
}

// ---------------- y += h; optionally zero next target ----------------
__global__ void add_zero_kernel(float* __restrict__ y,
                                const float* __restrict__ h,
                                float* __restrict__ z) {
    int i = blockIdx.x * blockDim.x + threadIdx.x;
    float4 a = ((const float4*)y)[i];
    float4 b = ((const float4*)h)[i];
    a.x += b.x; a.y += b.y; a.z += b.z; a.w += b.w;
    ((float4*)y)[i] = a;
    if (z) ((float4*)z)[i] = make_float4(0.f, 0.f, 0.f, 0.f);
}

// ---------------- GEMM1: H1 = relu((y*0.25) @ W1 + b1) ----------------
// M=50000, K=128, N=256. 64x64 block tile, 4x4 per thread, BK=32.
#define BM 64
#define BN 64
#define BK 32
__global__ void gemm1_kernel(const float* __restrict__ Y,
                             const float* __restrict__ W1,
                             const float* __restrict__ b1,
                             float* __restrict__ H1) {
    __shared__ float As[BM][BK + 1];
    __shared__ float Bs[BK][BN + 1];
    int tid = threadIdx.x;            // 256
    int tr = tid >> 4, tc = tid & 15; // 16x16
    int row0 = blockIdx.x * BM;
    int col0 = blockIdx.y * BN;
    float acc[4][4] = {};
    for (int k0 = 0; k0 < IN_DIM; k0 += BK) {
        for (int i = tid; i < BM * BK; i += 256) {
            int r = i >> 5, c = i & 31;   // BK=32
            int gr = row0 + r;
            As[r][c] = (gr < N_NODES) ? Y[gr * IN_DIM + k0 + c] * 0.25f : 0.f;
        }
        for (int i = tid; i < BK * BN; i += 256) {
            int r = i >> 6, c = i & 63;   // BN=64
            Bs[r][c] = W1[(k0 + r) * HID + col0 + c];
        }
        __syncthreads();
        #pragma unroll
        for (int kk = 0; kk < BK; ++kk) {
            float a[4], b[4];
            #pragma unroll
            for (int i = 0; i < 4; ++i) a[i] = As[tr * 4 + i][kk];
            #pragma unroll
            for (int j = 0; j < 4; ++j) b[j] = Bs[kk][tc * 4 + j];
            #pragma unroll
            for (int i = 0; i < 4; ++i)
                #pragma unroll
                for (int j = 0; j < 4; ++j)
                    acc[i][j] += a[i] * b[j];
        }
        __syncthreads();
    }
    #pragma unroll
    for (int i = 0; i < 4; ++i) {
        int gr = row0 + tr * 4 + i;
        if (gr >= N_NODES) continue;
        #pragma unroll
        for (int j = 0; j < 4; ++j) {
            int gc = col0 + tc * 4 + j;
            float v = acc[i][j] + b1[gc];
            H1[gr * HID + gc] = v > 0.f ? v : 0.f;
        }
    }
}

// ---------------- GEMM2 + double log_softmax ----------------
// One wave per row. W2 (256x40 fp32 = 40KB) staged in LDS.
__global__ void gemm2_lsm_kernel(const float* __restrict__ H1,
                                 const float* __restrict__ W2,
                                 const float* __restrict__ b2,
                                 float* __restrict__ Out) {
    __shared__ float w2s[HID * NCLASS];
    for (int i = threadIdx.x; i < HID * NCLASS; i += blockDim.x)
        w2s[i] = W2[i];
    __syncthreads();
    int wave = threadIdx.x >> 6;
    int lane = threadIdx.x & 63;
    int row = blockIdx.x * 4 + wave;
    if (row >= N_NODES) return;

    const float* h = H1 + row * HID;
    float acc;
    if (lane < NCLASS) {
        float s = 0.f;
        #pragma unroll 8
        for (int k = 0; k < HID; ++k)
            s += h[k] * w2s[k * NCLASS + lane];
        acc = s + b2[lane];
    } else {
        acc = -INFINITY;
    }

    // first log_softmax
    float m = acc;
    #pragma unroll
    for (int off = 32; off >= 1; off >>= 1)
        m = fmaxf(m, __shfl_xor(m, off));
    float ex = (lane < NCLASS) ? expf(acc - m) : 0.f;
    float s = ex;
    #pragma unroll
    for (int off = 32; off >= 1; off >>= 1)
        s += __shfl_xor(s, off);
    float z1 = acc - (m + logf(s));

    // second log_softmax (numerically ~no-op, replicate reference)
    float m2 = z1;
    #pragma unroll
    for (int off = 32; off >= 1; off >>= 1)
        m2 = fmaxf(m2, __shfl_xor(m2, off));
    float ex2 = (lane < NCLASS) ? expf(z1 - m2) : 0.f;
    float s2 = ex2;
    #pragma unroll
    for (int off = 32; off >= 1; off >>= 1)
        s2 += __shfl_xor(s2, off);
    float z2 = z1 - (m2 + logf(s2));

    if (lane < NCLASS)
        Out[row * NCLASS + lane] = z2;
}

extern "C" void kernel_launch(void* const* d_in, const int* in_sizes, int n_in,
                              void* d_out, int out_size, void* d_ws, size_t ws_size,
                              hipStream_t stream) {
    const float* feats   = (const float*)d_in[0];
    const int*   e_row   = (const int*)d_in[1];
    const int*   e_col   = (const int*)d_in[2];
    const float* e_vals  = (const float*)d_in[3];
    const float* W1      = (const float*)d_in[4];
    const float* b1      = (const float*)d_in[5];
    const float* W2      = (const float*)d_in[6];
    const float* b2      = (const float*)d_in[7];
    float* out = (float*)d_out;

    float* ws   = (float*)d_ws;
    float* y    = ws;                               // 6.4M floats
    float* bufA = ws + (size_t)N_NODES * IN_DIM;    // 6.4M
    float* bufB = bufA + (size_t)N_NODES * IN_DIM;  // 6.4M
    float* h1   = bufA;                             // 12.8M floats, reuses bufA+bufB after hops

    const int ELEMS4 = N_NODES * IN_DIM / 4;        // 1.6M float4
    const int VB = 256;
    const int VG = ELEMS4 / VB;                     // 6250 exact

    // x = 0.5*feats -> y, bufA; bufB = 0
    init_kernel<<<VG, VB, 0, stream>>>(feats, y, bufA, bufB);

    const int ST = N_EDGES * 32;
    const int SG = ST / 256;                        // 100000 exact

    // hop 1: bufB = A @ bufA ; y += bufB ; zero bufA
    spmm_atomic<<<SG, 256, 0, stream>>>(e_row, e_col, e_vals, bufA, bufB);
    add_zero_kernel<<<VG, VB, 0, stream>>>(y, bufB, bufA);
    // hop 2: bufA = A @ bufB ; y += bufA ; zero bufB
    spmm_atomic<<<SG, 256, 0, stream>>>(e_row, e_col, e_vals, bufB, bufA);
    add_zero_kernel<<<VG, VB, 0, stream>>>(y, bufA, bufB);
    // hop 3: bufB = A @ bufA ; y += bufB
    spmm_atomic<<<SG, 256, 0, stream>>>(e_row, e_col, e_vals, bufA, bufB);
    add_zero_kernel<<<VG, VB, 0, stream>>>(y, bufB, nullptr);

    // GEMM1: h1 = relu((y*0.25) @ W1 + b1)
    dim3 g1((N_NODES + BM - 1) / BM, HID / BN);     // (782, 4)
    gemm1_kernel<<<g1, 256, 0, stream>>>(y, W1, b1, h1);

    // GEMM2 + double log_softmax -> out
    gemm2_lsm_kernel<<<N_NODES / 4, 256, 0, stream>>>(h1, W2, b2, out);
}

// Round 2
// 790.787 us; speedup vs baseline: 5.6005x; 5.6005x over previous
//
#include <hip/hip_runtime.h>
#include <math.h>

#define N_NODES 50000
#define N_EDGES 800000
#define IN_DIM 128
#define HID 256
#define NCLASS 40

// ---------------- init: y = bufA = 0.5*feats; counts = 0 ----------------
__global__ void init_kernel(const float* __restrict__ feats,
                            float* __restrict__ y,
                            float* __restrict__ bufA,
                            int* __restrict__ counts) {
    int i = blockIdx.x * blockDim.x + threadIdx.x;   // float4 index, 1.6M total
    const float4* f4 = (const float4*)feats;
    float4 v = f4[i];
    v.x *= 0.5f; v.y *= 0.5f; v.z *= 0.5f; v.w *= 0.5f;
    ((float4*)y)[i] = v;
    ((float4*)bufA)[i] = v;
    if (i < N_NODES) counts[i] = 0;
}

// ---------------- CSR build: count ----------------
__global__ void count_kernel(const int* __restrict__ rows,
                             int* __restrict__ counts) {
    int e = blockIdx.x * blockDim.x + threadIdx.x;
    if (e < N_EDGES) atomicAdd(&counts[rows[e]], 1);
}

// ---------------- CSR build: one-block exclusive scan ----------------
#define SCAN_T 1024
__global__ void scan_kernel(const int* __restrict__ counts,
                            int* __restrict__ row_start,
                            int* __restrict__ cursor) {
    __shared__ int partial[SCAN_T];
    int tid = threadIdx.x;
    const int CHUNK = (N_NODES + SCAN_T - 1) / SCAN_T;  // 49
    int base = tid * CHUNK;
    int s = 0;
    for (int i = 0; i < CHUNK; ++i) {
        int idx = base + i;
        if (idx < N_NODES) s += counts[idx];
    }
    partial[tid] = s;
    __syncthreads();
    for (int off = 1; off < SCAN_T; off <<= 1) {
        int v = (tid >= off) ? partial[tid - off] : 0;
        __syncthreads();
        partial[tid] += v;
        __syncthreads();
    }
    int run = (tid > 0) ? partial[tid - 1] : 0;
    for (int i = 0; i < CHUNK; ++i) {
        int idx = base + i;
        if (idx < N_NODES) {
            row_start[idx] = run;
            cursor[idx] = run;
            run += counts[idx];
        }
    }
    if (tid == SCAN_T - 1) row_start[N_NODES] = partial[SCAN_T - 1];
}

// ---------------- CSR build: scatter ----------------
__global__ void scatter_kernel(const int* __restrict__ rows,
                               const int* __restrict__ cols,
                               const float* __restrict__ vals,
                               int* __restrict__ cursor,
                               int* __restrict__ csr_col,
                               float* __restrict__ csr_val) {
    int e = blockIdx.x * blockDim.x + threadIdx.x;
    if (e >= N_EDGES) return;
    int pos = atomicAdd(&cursor[rows[e]], 1);
    csr_col[pos] = cols[e];
    csr_val[pos] = vals[e];
}

// ---------------- SpMM (CSR, atomic-free): Hout[r] = sum val*Hin[col]; y[r] += Hout[r]
// One 64-lane wave per row; lane owns float2 at dim 2*lane.
__global__ void spmm_csr(const int* __restrict__ row_start,
                         const int* __restrict__ csr_col,
                         const float* __restrict__ csr_val,
                         const float* __restrict__ Hin,
                         float* __restrict__ Hout,
                         float* __restrict__ y) {
    int wave = (blockIdx.x * blockDim.x + threadIdx.x) >> 6;
    int lane = threadIdx.x & 63;
    if (wave >= N_NODES) return;
    int start = row_start[wave];
    int end   = row_start[wave + 1];
    float2 acc = make_float2(0.f, 0.f);
    for (int base = start; base < end; base += 64) {
        int idx = base + lane;
        int c = 0; float v = 0.f;
        if (idx < end) { c = csr_col[idx]; v = csr_val[idx]; }
        int cnt = min(64, end - base);
        for (int j = 0; j < cnt; ++j) {
            int   cj = __shfl(c, j);
            float vj = __shfl(v, j);
            float2 h = *(const float2*)(Hin + (size_t)cj * IN_DIM + lane * 2);
            acc.x += vj * h.x;
            acc.y += vj * h.y;
        }
    }
    size_t o = (size_t)wave * IN_DIM + lane * 2;
    *(float2*)(Hout + o) = acc;
    float2 yo = *(const float2*)(y + o);
    yo.x += acc.x; yo.y += acc.y;
    *(float2*)(y + o) = yo;
}

// ---------------- GEMM1: H1 = relu((y*0.25) @ W1 + b1) ----------------
#define BM 64
#define BN 64
#define BK 32
__global__ void gemm1_kernel(const float* __restrict__ Y,
                             const float* __restrict__ W1,
                             const float* __restrict__ b1,
                             float* __restrict__ H1) {
    __shared__ float As[BM][BK + 1];
    __shared__ float Bs[BK][BN + 1];
    int tid = threadIdx.x;            // 256
    int tr = tid >> 4, tc = tid & 15; // 16x16
    int row0 = blockIdx.x * BM;
    int col0 = blockIdx.y * BN;
    float acc[4][4] = {};
    for (int k0 = 0; k0 < IN_DIM; k0 += BK) {
        for (int i = tid; i < BM * BK; i += 256) {
            int r = i >> 5, c = i & 31;
            int gr = row0 + r;
            As[r][c] = (gr < N_NODES) ? Y[gr * IN_DIM + k0 + c] * 0.25f : 0.f;
        }
        for (int i = tid; i < BK * BN; i += 256) {
            int r = i >> 6, c = i & 63;
            Bs[r][c] = W1[(k0 + r) * HID + col0 + c];
        }
        __syncthreads();
        #pragma unroll
        for (int kk = 0; kk < BK; ++kk) {
            float a[4], b[4];
            #pragma unroll
            for (int i = 0; i < 4; ++i) a[i] = As[tr * 4 + i][kk];
            #pragma unroll
            for (int j = 0; j < 4; ++j) b[j] = Bs[kk][tc * 4 + j];
            #pragma unroll
            for (int i = 0; i < 4; ++i)
                #pragma unroll
                for (int j = 0; j < 4; ++j)
                    acc[i][j] += a[i] * b[j];
        }
        __syncthreads();
    }
    #pragma unroll
    for (int i = 0; i < 4; ++i) {
        int gr = row0 + tr * 4 + i;
        if (gr >= N_NODES) continue;
        #pragma unroll
        for (int j = 0; j < 4; ++j) {
            int gc = col0 + tc * 4 + j;
            float v = acc[i][j] + b1[gc];
            H1[gr * HID + gc] = v > 0.f ? v : 0.f;
        }
    }
}

// ---------------- GEMM2 + double log_softmax ----------------
__global__ void gemm2_lsm_kernel(const float* __restrict__ H1,
                                 const float* __restrict__ W2,
                                 const float* __restrict__ b2,
                                 float* __restrict__ Out) {
    __shared__ float w2s[HID * NCLASS];
    for (int i = threadIdx.x; i < HID * NCLASS; i += blockDim.x)
        w2s[i] = W2[i];
    __syncthreads();
    int wave = threadIdx.x >> 6;
    int lane = threadIdx.x & 63;
    int row = blockIdx.x * 4 + wave;
    if (row >= N_NODES) return;

    const float* h = H1 + (size_t)row * HID;
    float acc;
    if (lane < NCLASS) {
        float s = 0.f;
        #pragma unroll 8
        for (int k = 0; k < HID; ++k)
            s += h[k] * w2s[k * NCLASS + lane];
        acc = s + b2[lane];
    } else {
        acc = -INFINITY;
    }

    float m = acc;
    #pragma unroll
    for (int off = 32; off >= 1; off >>= 1)
        m = fmaxf(m, __shfl_xor(m, off));
    float ex = (lane < NCLASS) ? expf(acc - m) : 0.f;
    float s = ex;
    #pragma unroll
    for (int off = 32; off >= 1; off >>= 1)
        s += __shfl_xor(s, off);
    float z1 = acc - (m + logf(s));

    float m2 = z1;
    #pragma unroll
    for (int off = 32; off >= 1; off >>= 1)
        m2 = fmaxf(m2, __shfl_xor(m2, off));
    float ex2 = (lane < NCLASS) ? expf(z1 - m2) : 0.f;
    float s2 = ex2;
    #pragma unroll
    for (int off = 32; off >= 1; off >>= 1)
        s2 += __shfl_xor(s2, off);
    float z2 = z1 - (m2 + logf(s2));

    if (lane < NCLASS)
        Out[(size_t)row * NCLASS + lane] = z2;
}

extern "C" void kernel_launch(void* const* d_in, const int* in_sizes, int n_in,
                              void* d_out, int out_size, void* d_ws, size_t ws_size,
                              hipStream_t stream) {
    const float* feats   = (const float*)d_in[0];
    const int*   e_row   = (const int*)d_in[1];
    const int*   e_col   = (const int*)d_in[2];
    const float* e_vals  = (const float*)d_in[3];
    const float* W1      = (const float*)d_in[4];
    const float* b1      = (const float*)d_in[5];
    const float* W2      = (const float*)d_in[6];
    const float* b2      = (const float*)d_in[7];
    float* out = (float*)d_out;

    // Workspace: y | bufA | bufB  (h1 reuses bufA+bufB after hops)
    float* ws   = (float*)d_ws;
    float* y    = ws;
    float* bufA = ws + (size_t)N_NODES * IN_DIM;
    float* bufB = bufA + (size_t)N_NODES * IN_DIM;
    float* h1   = bufA;

    // CSR scratch lives in d_out (8 MB; dead until gemm2 overwrites all of it)
    int*   csr_col   = (int*)d_out;                    // 800000
    float* csr_val   = (float*)d_out + N_EDGES;        // 800000
    int*   counts    = (int*)d_out + 2 * N_EDGES;      // 50000
    int*   row_start = counts + N_NODES;               // 50001
    int*   cursor    = row_start + N_NODES + 1;        // 50000
    // total: 1,750,001 elements < out_size (2,000,000)

    const int ELEMS4 = N_NODES * IN_DIM / 4;  // 1.6M
    const int VG = ELEMS4 / 256;              // 6250 exact

    // x = 0.5*feats -> y, bufA; zero counts
    init_kernel<<<VG, 256, 0, stream>>>(feats, y, bufA, counts);

    // Build CSR
    const int EG = N_EDGES / 256;             // 3125 exact
    count_kernel<<<EG, 256, 0, stream>>>(e_row, counts);
    scan_kernel<<<1, SCAN_T, 0, stream>>>(counts, row_start, cursor);
    scatter_kernel<<<EG, 256, 0, stream>>>(e_row, e_col, e_vals, cursor, csr_col, csr_val);

    // 3 propagation hops, y-accumulate fused, no atomics, no zeroing
    const int SPMM_BLOCKS = N_NODES / 4;      // 12500 (4 waves/block)
    spmm_csr<<<SPMM_BLOCKS, 256, 0, stream>>>(row_start, csr_col, csr_val, bufA, bufB, y);
    spmm_csr<<<SPMM_BLOCKS, 256, 0, stream>>>(row_start, csr_col, csr_val, bufB, bufA, y);
    spmm_csr<<<SPMM_BLOCKS, 256, 0, stream>>>(row_start, csr_col, csr_val, bufA, bufB, y);

    // GEMM1: h1 = relu((y*0.25) @ W1 + b1)
    dim3 g1((N_NODES + BM - 1) / BM, HID / BN);
    gemm1_kernel<<<g1, 256, 0, stream>>>(y, W1, b1, h1);

    // GEMM2 + double log_softmax -> out (overwrites CSR scratch entirely)
    gemm2_lsm_kernel<<<N_NODES / 4, 256, 0, stream>>>(h1, W2, b2, out);
}

// Round 3
// 667.671 us; speedup vs baseline: 6.6332x; 1.1844x over previous
//
#include <hip/hip_runtime.h>
#include <math.h>

#define N_NODES 50000
#define N_EDGES 800000
#define IN_DIM 128
#define HID 256
#define NCLASS 40

// ---------------- init: y = bufA = 0.5*feats; counts = 0 ----------------
__global__ void init_kernel(const float* __restrict__ feats,
                            float* __restrict__ y,
                            float* __restrict__ bufA,
                            int* __restrict__ counts) {
    int i = blockIdx.x * blockDim.x + threadIdx.x;   // float4 index, 1.6M total
    const float4* f4 = (const float4*)feats;
    float4 v = f4[i];
    v.x *= 0.5f; v.y *= 0.5f; v.z *= 0.5f; v.w *= 0.5f;
    ((float4*)y)[i] = v;
    ((float4*)bufA)[i] = v;
    if (i < N_NODES) counts[i] = 0;
}

// ---------------- CSR build: count ----------------
__global__ void count_kernel(const int* __restrict__ rows,
                             int* __restrict__ counts) {
    int e = blockIdx.x * blockDim.x + threadIdx.x;
    if (e < N_EDGES) atomicAdd(&counts[rows[e]], 1);
}

// ---------------- CSR build: one-block exclusive scan ----------------
#define SCAN_T 1024
__global__ void scan_kernel(const int* __restrict__ counts,
                            int* __restrict__ row_start,
                            int* __restrict__ cursor) {
    __shared__ int partial[SCAN_T];
    int tid = threadIdx.x;
    const int CHUNK = (N_NODES + SCAN_T - 1) / SCAN_T;  // 49
    int base = tid * CHUNK;
    int s = 0;
    for (int i = 0; i < CHUNK; ++i) {
        int idx = base + i;
        if (idx < N_NODES) s += counts[idx];
    }
    partial[tid] = s;
    __syncthreads();
    for (int off = 1; off < SCAN_T; off <<= 1) {
        int v = (tid >= off) ? partial[tid - off] : 0;
        __syncthreads();
        partial[tid] += v;
        __syncthreads();
    }
    int run = (tid > 0) ? partial[tid - 1] : 0;
    for (int i = 0; i < CHUNK; ++i) {
        int idx = base + i;
        if (idx < N_NODES) {
            row_start[idx] = run;
            cursor[idx] = run;
            run += counts[idx];
        }
    }
    if (tid == SCAN_T - 1) row_start[N_NODES] = partial[SCAN_T - 1];
}

// ---------------- CSR build: scatter ----------------
__global__ void scatter_kernel(const int* __restrict__ rows,
                               const int* __restrict__ cols,
                               const float* __restrict__ vals,
                               int* __restrict__ cursor,
                               int* __restrict__ csr_col,
                               float* __restrict__ csr_val) {
    int e = blockIdx.x * blockDim.x + threadIdx.x;
    if (e >= N_EDGES) return;
    int pos = atomicAdd(&cursor[rows[e]], 1);
    csr_col[pos] = cols[e];
    csr_val[pos] = vals[e];
}

// ---------------- SpMM (CSR, atomic-free): Hout[r] = sum val*Hin[col]; y[r] += Hout[r]
// One 64-lane wave per row; lane owns float2 at dim 2*lane.
__global__ void spmm_csr(const int* __restrict__ row_start,
                         const int* __restrict__ csr_col,
                         const float* __restrict__ csr_val,
                         const float* __restrict__ Hin,
                         float* __restrict__ Hout,
                         float* __restrict__ y) {
    int wave = (blockIdx.x * blockDim.x + threadIdx.x) >> 6;
    int lane = threadIdx.x & 63;
    if (wave >= N_NODES) return;
    int start = row_start[wave];
    int end   = row_start[wave + 1];
    float2 acc = make_float2(0.f, 0.f);
    for (int base = start; base < end; base += 64) {
        int idx = base + lane;
        int c = 0; float v = 0.f;
        if (idx < end) { c = csr_col[idx]; v = csr_val[idx]; }
        int cnt = min(64, end - base);
        for (int j = 0; j < cnt; ++j) {
            int   cj = __shfl(c, j);
            float vj = __shfl(v, j);
            float2 h = *(const float2*)(Hin + (size_t)cj * IN_DIM + lane * 2);
            acc.x += vj * h.x;
            acc.y += vj * h.y;
        }
    }
    size_t o = (size_t)wave * IN_DIM + lane * 2;
    *(float2*)(Hout + o) = acc;
    float2 yo = *(const float2*)(y + o);
    yo.x += acc.x; yo.y += acc.y;
    *(float2*)(y + o) = yo;
}

// ---------------- GEMM1: H1 = relu((y*0.25) @ W1 + b1) ----------------
#define BM 64
#define BN 64
#define BK 32
__global__ void gemm1_kernel(const float* __restrict__ Y,
                             const float* __restrict__ W1,
                             const float* __restrict__ b1,
                             float* __restrict__ H1) {
    __shared__ float As[BM][BK + 1];
    __shared__ float Bs[BK][BN + 1];
    int tid = threadIdx.x;            // 256
    int tr = tid >> 4, tc = tid & 15; // 16x16
    int row0 = blockIdx.x * BM;
    int col0 = blockIdx.y * BN;
    float acc[4][4] = {};
    for (int k0 = 0; k0 < IN_DIM; k0 += BK) {
        for (int i = tid; i < BM * BK; i += 256) {
            int r = i >> 5, c = i & 31;
            int gr = row0 + r;
            As[r][c] = (gr < N_NODES) ? Y[gr * IN_DIM + k0 + c] * 0.25f : 0.f;
        }
        for (int i = tid; i < BK * BN; i += 256) {
            int r = i >> 6, c = i & 63;
            Bs[r][c] = W1[(k0 + r) * HID + col0 + c];
        }
        __syncthreads();
        #pragma unroll
        for (int kk = 0; kk < BK; ++kk) {
            float a[4], b[4];
            #pragma unroll
            for (int i = 0; i < 4; ++i) a[i] = As[tr * 4 + i][kk];
            #pragma unroll
            for (int j = 0; j < 4; ++j) b[j] = Bs[kk][tc * 4 + j];
            #pragma unroll
            for (int i = 0; i < 4; ++i)
                #pragma unroll
                for (int j = 0; j < 4; ++j)
                    acc[i][j] += a[i] * b[j];
        }
        __syncthreads();
    }
    #pragma unroll
    for (int i = 0; i < 4; ++i) {
        int gr = row0 + tr * 4 + i;
        if (gr >= N_NODES) continue;
        #pragma unroll
        for (int j = 0; j < 4; ++j) {
            int gc = col0 + tc * 4 + j;
            float v = acc[i][j] + b1[gc];
            H1[gr * HID + gc] = v > 0.f ? v : 0.f;
        }
    }
}

// ---------------- GEMM2: logits = H1 @ W2 + b2  (tiled, NCLASS padded to 64) ----------------
__global__ void gemm2_kernel(const float* __restrict__ H1,
                             const float* __restrict__ W2,
                             const float* __restrict__ b2,
                             float* __restrict__ logits) {
    __shared__ float As[BM][BK + 1];   // 64 x 32
    __shared__ float Bs[BK][BN + 1];   // 32 x 64 (cols >= 40 are zero pad)
    int tid = threadIdx.x;            // 256
    int tr = tid >> 4, tc = tid & 15;
    int row0 = blockIdx.x * BM;
    float acc[4][4] = {};
    for (int k0 = 0; k0 < HID; k0 += BK) {   // 8 k-tiles
        for (int i = tid; i < BM * BK; i += 256) {
            int r = i >> 5, c = i & 31;
            int gr = row0 + r;
            As[r][c] = (gr < N_NODES) ? H1[(size_t)gr * HID + k0 + c] : 0.f;
        }
        for (int i = tid; i < BK * BN; i += 256) {
            int r = i >> 6, c = i & 63;
            Bs[r][c] = (c < NCLASS) ? W2[(size_t)(k0 + r) * NCLASS + c] : 0.f;
        }
        __syncthreads();
        #pragma unroll
        for (int kk = 0; kk < BK; ++kk) {
            float a[4], b[4];
            #pragma unroll
            for (int i = 0; i < 4; ++i) a[i] = As[tr * 4 + i][kk];
            #pragma unroll
            for (int j = 0; j < 4; ++j) b[j] = Bs[kk][tc * 4 + j];
            #pragma unroll
            for (int i = 0; i < 4; ++i)
                #pragma unroll
                for (int j = 0; j < 4; ++j)
                    acc[i][j] += a[i] * b[j];
        }
        __syncthreads();
    }
    #pragma unroll
    for (int i = 0; i < 4; ++i) {
        int gr = row0 + tr * 4 + i;
        if (gr >= N_NODES) continue;
        #pragma unroll
        for (int j = 0; j < 4; ++j) {
            int gc = tc * 4 + j;
            if (gc < NCLASS)
                logits[(size_t)gr * NCLASS + gc] = acc[i][j] + b2[gc];
        }
    }
}

// ---------------- double log_softmax over 40 classes, wave per row ----------------
__global__ void lsm_kernel(const float* __restrict__ logits,
                           float* __restrict__ Out) {
    int wave = threadIdx.x >> 6;
    int lane = threadIdx.x & 63;
    int row = blockIdx.x * 4 + wave;
    if (row >= N_NODES) return;

    float acc = (lane < NCLASS) ? logits[(size_t)row * NCLASS + lane] : -INFINITY;

    float m = acc;
    #pragma unroll
    for (int off = 32; off >= 1; off >>= 1)
        m = fmaxf(m, __shfl_xor(m, off));
    float ex = (lane < NCLASS) ? expf(acc - m) : 0.f;
    float s = ex;
    #pragma unroll
    for (int off = 32; off >= 1; off >>= 1)
        s += __shfl_xor(s, off);
    float z1 = acc - (m + logf(s));

    float m2 = z1;
    #pragma unroll
    for (int off = 32; off >= 1; off >>= 1)
        m2 = fmaxf(m2, __shfl_xor(m2, off));
    float ex2 = (lane < NCLASS) ? expf(z1 - m2) : 0.f;
    float s2 = ex2;
    #pragma unroll
    for (int off = 32; off >= 1; off >>= 1)
        s2 += __shfl_xor(s2, off);
    float z2 = z1 - (m2 + logf(s2));

    if (lane < NCLASS)
        Out[(size_t)row * NCLASS + lane] = z2;
}

extern "C" void kernel_launch(void* const* d_in, const int* in_sizes, int n_in,
                              void* d_out, int out_size, void* d_ws, size_t ws_size,
                              hipStream_t stream) {
    const float* feats   = (const float*)d_in[0];
    const int*   e_row   = (const int*)d_in[1];
    const int*   e_col   = (const int*)d_in[2];
    const float* e_vals  = (const float*)d_in[3];
    const float* W1      = (const float*)d_in[4];
    const float* b1      = (const float*)d_in[5];
    const float* W2      = (const float*)d_in[6];
    const float* b2      = (const float*)d_in[7];
    float* out = (float*)d_out;

    // Workspace: y | bufA | bufB  (h1 reuses bufA+bufB after hops;
    // logits reuses y after gemm1 consumed it)
    float* ws   = (float*)d_ws;
    float* y    = ws;
    float* bufA = ws + (size_t)N_NODES * IN_DIM;
    float* bufB = bufA + (size_t)N_NODES * IN_DIM;
    float* h1   = bufA;
    float* logits = y;   // 2M floats, y is dead after gemm1

    // CSR scratch lives in d_out (8 MB; fully overwritten by lsm_kernel at the end)
    int*   csr_col   = (int*)d_out;                    // 800000
    float* csr_val   = (float*)d_out + N_EDGES;        // 800000
    int*   counts    = (int*)d_out + 2 * N_EDGES;      // 50000
    int*   row_start = counts + N_NODES;               // 50001
    int*   cursor    = row_start + N_NODES + 1;        // 50000

    const int ELEMS4 = N_NODES * IN_DIM / 4;  // 1.6M
    const int VG = ELEMS4 / 256;              // 6250 exact

    // x = 0.5*feats -> y, bufA; zero counts
    init_kernel<<<VG, 256, 0, stream>>>(feats, y, bufA, counts);

    // Build CSR
    const int EG = N_EDGES / 256;             // 3125 exact
    count_kernel<<<EG, 256, 0, stream>>>(e_row, counts);
    scan_kernel<<<1, SCAN_T, 0, stream>>>(counts, row_start, cursor);
    scatter_kernel<<<EG, 256, 0, stream>>>(e_row, e_col, e_vals, cursor, csr_col, csr_val);

    // 3 propagation hops, y-accumulate fused, no atomics, no zeroing
    const int SPMM_BLOCKS = N_NODES / 4;      // 12500 (4 waves/block)
    spmm_csr<<<SPMM_BLOCKS, 256, 0, stream>>>(row_start, csr_col, csr_val, bufA, bufB, y);
    spmm_csr<<<SPMM_BLOCKS, 256, 0, stream>>>(row_start, csr_col, csr_val, bufB, bufA, y);
    spmm_csr<<<SPMM_BLOCKS, 256, 0, stream>>>(row_start, csr_col, csr_val, bufA, bufB, y);

    // GEMM1: h1 = relu((y*0.25) @ W1 + b1)
    dim3 g1((N_NODES + BM - 1) / BM, HID / BN);
    gemm1_kernel<<<g1, 256, 0, stream>>>(y, W1, b1, h1);

    // GEMM2: logits = h1 @ W2 + b2  (into dead y region)
    dim3 g2((N_NODES + BM - 1) / BM, 1);
    gemm2_kernel<<<g2, 256, 0, stream>>>(h1, W2, b2, logits);

    // double log_softmax -> out (overwrites CSR scratch entirely)
    lsm_kernel<<<(N_NODES + 3) / 4, 256, 0, stream>>>(logits, out);
}

// Round 4
// 555.486 us; speedup vs baseline: 7.9728x; 1.2020x over previous
//
#include <hip/hip_runtime.h>
#include <math.h>

#define N_NODES 50000
#define N_EDGES 800000
#define IN_DIM 128
#define HID 256
#define NCLASS 40

#define SCAN_NBLK 49   // ceil(50000 / 1024)

// ---------------- init: y = bufA = 0.5*feats; counts = 0 ----------------
__global__ void init_kernel(const float* __restrict__ feats,
                            float* __restrict__ y,
                            float* __restrict__ bufA,
                            int* __restrict__ counts) {
    int i = blockIdx.x * blockDim.x + threadIdx.x;   // float4 index, 1.6M total
    const float4* f4 = (const float4*)feats;
    float4 v = f4[i];
    v.x *= 0.5f; v.y *= 0.5f; v.z *= 0.5f; v.w *= 0.5f;
    ((float4*)y)[i] = v;
    ((float4*)bufA)[i] = v;
    if (i < N_NODES) counts[i] = 0;
}

// ---------------- CSR build: count ----------------
__global__ void count_kernel(const int* __restrict__ rows,
                             int* __restrict__ counts) {
    int e = blockIdx.x * blockDim.x + threadIdx.x;
    if (e < N_EDGES) atomicAdd(&counts[rows[e]], 1);
}

// ---------------- hierarchical scan, phase 1: per-block sums ----------------
// 49 blocks x 256 threads; each thread sums 4 consecutive counts (int4).
__global__ void block_sum_kernel(const int* __restrict__ counts,
                                 int* __restrict__ blockSums) {
    int t = threadIdx.x;
    int base = blockIdx.x * 1024 + t * 4;
    int s = 0;
    if (base < N_NODES) {            // N_NODES % 4 == 0, so full int4 or nothing
        int4 c = *(const int4*)(counts + base);
        s = c.x + c.y + c.z + c.w;
    }
    // wave reduce
    #pragma unroll
    for (int off = 32; off >= 1; off >>= 1)
        s += __shfl_xor(s, off);
    __shared__ int wsum[4];
    int lane = t & 63, wid = t >> 6;
    if (lane == 0) wsum[wid] = s;
    __syncthreads();
    if (t == 0)
        blockSums[blockIdx.x] = wsum[0] + wsum[1] + wsum[2] + wsum[3];
}

// ---------------- phase 2: scan the 49 block sums (single wave) ----------------
__global__ void block_offset_kernel(const int* __restrict__ blockSums,
                                    int* __restrict__ blockOffs,
                                    int* __restrict__ row_start) {
    int lane = threadIdx.x;          // 64 threads
    int x = (lane < SCAN_NBLK) ? blockSums[lane] : 0;
    #pragma unroll
    for (int off = 1; off < 64; off <<= 1) {
        int y = __shfl_up(x, off);
        if (lane >= off) x += y;
    }
    int excl = __shfl_up(x, 1);
    if (lane == 0) excl = 0;
    if (lane < SCAN_NBLK) blockOffs[lane] = excl;
    if (lane == SCAN_NBLK - 1) row_start[N_NODES] = x;   // grand total
}

// ---------------- phase 3: local scan + block offset -> row_start, cursor ----------------
__global__ void local_scan_kernel(const int* __restrict__ counts,
                                  const int* __restrict__ blockOffs,
                                  int* __restrict__ row_start,
                                  int* __restrict__ cursor) {
    int t = threadIdx.x;
    int base = blockIdx.x * 1024 + t * 4;
    int4 c = make_int4(0, 0, 0, 0);
    if (base < N_NODES) c = *(const int4*)(counts + base);
    int s0 = c.x, s1 = s0 + c.y, s2 = s1 + c.z, s3 = s2 + c.w;  // inclusive in-thread
    int tsum = s3;
    int lane = t & 63, wid = t >> 6;
    int x = tsum;
    #pragma unroll
    for (int off = 1; off < 64; off <<= 1) {
        int y = __shfl_up(x, off);
        if (lane >= off) x += y;
    }
    __shared__ int wsum[4];
    if (lane == 63) wsum[wid] = x;
    __syncthreads();
    int woff = 0;
    for (int i = 0; i < 4; ++i)
        if (i < wid) woff += wsum[i];
    int excl = x - tsum + woff + blockOffs[blockIdx.x];
    if (base < N_NODES) {
        int4 rs = make_int4(excl, excl + s0, excl + s1, excl + s2);
        *(int4*)(row_start + base) = rs;
        *(int4*)(cursor + base) = rs;
    }
}

// ---------------- CSR build: scatter ----------------
__global__ void scatter_kernel(const int* __restrict__ rows,
                               const int* __restrict__ cols,
                               const float* __restrict__ vals,
                               int* __restrict__ cursor,
                               int* __restrict__ csr_col,
                               float* __restrict__ csr_val) {
    int e = blockIdx.x * blockDim.x + threadIdx.x;
    if (e >= N_EDGES) return;
    int pos = atomicAdd(&cursor[rows[e]], 1);
    csr_col[pos] = cols[e];
    csr_val[pos] = vals[e];
}

// ---------------- SpMM (CSR, atomic-free): Hout[r] = sum val*Hin[col]; y[r] += Hout[r]
// One 64-lane wave per row; lane owns float2 at dim 2*lane.
__global__ void spmm_csr(const int* __restrict__ row_start,
                         const int* __restrict__ csr_col,
                         const float* __restrict__ csr_val,
                         const float* __restrict__ Hin,
                         float* __restrict__ Hout,
                         float* __restrict__ y) {
    int wave = (blockIdx.x * blockDim.x + threadIdx.x) >> 6;
    int lane = threadIdx.x & 63;
    if (wave >= N_NODES) return;
    int start = row_start[wave];
    int end   = row_start[wave + 1];
    float2 acc = make_float2(0.f, 0.f);
    for (int base = start; base < end; base += 64) {
        int idx = base + lane;
        int c = 0; float v = 0.f;
        if (idx < end) { c = csr_col[idx]; v = csr_val[idx]; }
        int cnt = min(64, end - base);
        for (int j = 0; j < cnt; ++j) {
            int   cj = __shfl(c, j);
            float vj = __shfl(v, j);
            float2 h = *(const float2*)(Hin + (size_t)cj * IN_DIM + lane * 2);
            acc.x += vj * h.x;
            acc.y += vj * h.y;
        }
    }
    size_t o = (size_t)wave * IN_DIM + lane * 2;
    *(float2*)(Hout + o) = acc;
    float2 yo = *(const float2*)(y + o);
    yo.x += acc.x; yo.y += acc.y;
    *(float2*)(y + o) = yo;
}

// ---------------- GEMM1: H1 = relu((y*0.25) @ W1 + b1) ----------------
#define BM 64
#define BN 64
#define BK 32
__global__ void gemm1_kernel(const float* __restrict__ Y,
                             const float* __restrict__ W1,
                             const float* __restrict__ b1,
                             float* __restrict__ H1) {
    __shared__ float As[BM][BK + 1];
    __shared__ float Bs[BK][BN + 1];
    int tid = threadIdx.x;            // 256
    int tr = tid >> 4, tc = tid & 15; // 16x16
    int row0 = blockIdx.x * BM;
    int col0 = blockIdx.y * BN;
    float acc[4][4] = {};
    for (int k0 = 0; k0 < IN_DIM; k0 += BK) {
        for (int i = tid; i < BM * BK; i += 256) {
            int r = i >> 5, c = i & 31;
            int gr = row0 + r;
            As[r][c] = (gr < N_NODES) ? Y[gr * IN_DIM + k0 + c] * 0.25f : 0.f;
        }
        for (int i = tid; i < BK * BN; i += 256) {
            int r = i >> 6, c = i & 63;
            Bs[r][c] = W1[(k0 + r) * HID + col0 + c];
        }
        __syncthreads();
        #pragma unroll
        for (int kk = 0; kk < BK; ++kk) {
            float a[4], b[4];
            #pragma unroll
            for (int i = 0; i < 4; ++i) a[i] = As[tr * 4 + i][kk];
            #pragma unroll
            for (int j = 0; j < 4; ++j) b[j] = Bs[kk][tc * 4 + j];
            #pragma unroll
            for (int i = 0; i < 4; ++i)
                #pragma unroll
                for (int j = 0; j < 4; ++j)
                    acc[i][j] += a[i] * b[j];
        }
        __syncthreads();
    }
    #pragma unroll
    for (int i = 0; i < 4; ++i) {
        int gr = row0 + tr * 4 + i;
        if (gr >= N_NODES) continue;
        #pragma unroll
        for (int j = 0; j < 4; ++j) {
            int gc = col0 + tc * 4 + j;
            float v = acc[i][j] + b1[gc];
            H1[gr * HID + gc] = v > 0.f ? v : 0.f;
        }
    }
}

// ---------------- GEMM2: logits = H1 @ W2 + b2  (tiled, NCLASS padded to 64) ----------------
__global__ void gemm2_kernel(const float* __restrict__ H1,
                             const float* __restrict__ W2,
                             const float* __restrict__ b2,
                             float* __restrict__ logits) {
    __shared__ float As[BM][BK + 1];   // 64 x 32
    __shared__ float Bs[BK][BN + 1];   // 32 x 64 (cols >= 40 are zero pad)
    int tid = threadIdx.x;            // 256
    int tr = tid >> 4, tc = tid & 15;
    int row0 = blockIdx.x * BM;
    float acc[4][4] = {};
    for (int k0 = 0; k0 < HID; k0 += BK) {   // 8 k-tiles
        for (int i = tid; i < BM * BK; i += 256) {
            int r = i >> 5, c = i & 31;
            int gr = row0 + r;
            As[r][c] = (gr < N_NODES) ? H1[(size_t)gr * HID + k0 + c] : 0.f;
        }
        for (int i = tid; i < BK * BN; i += 256) {
            int r = i >> 6, c = i & 63;
            Bs[r][c] = (c < NCLASS) ? W2[(size_t)(k0 + r) * NCLASS + c] : 0.f;
        }
        __syncthreads();
        #pragma unroll
        for (int kk = 0; kk < BK; ++kk) {
            float a[4], b[4];
            #pragma unroll
            for (int i = 0; i < 4; ++i) a[i] = As[tr * 4 + i][kk];
            #pragma unroll
            for (int j = 0; j < 4; ++j) b[j] = Bs[kk][tc * 4 + j];
            #pragma unroll
            for (int i = 0; i < 4; ++i)
                #pragma unroll
                for (int j = 0; j < 4; ++j)
                    acc[i][j] += a[i] * b[j];
        }
        __syncthreads();
    }
    #pragma unroll
    for (int i = 0; i < 4; ++i) {
        int gr = row0 + tr * 4 + i;
        if (gr >= N_NODES) continue;
        #pragma unroll
        for (int j = 0; j < 4; ++j) {
            int gc = tc * 4 + j;
            if (gc < NCLASS)
                logits[(size_t)gr * NCLASS + gc] = acc[i][j] + b2[gc];
        }
    }
}

// ---------------- double log_softmax over 40 classes, wave per row ----------------
__global__ void lsm_kernel(const float* __restrict__ logits,
                           float* __restrict__ Out) {
    int wave = threadIdx.x >> 6;
    int lane = threadIdx.x & 63;
    int row = blockIdx.x * 4 + wave;
    if (row >= N_NODES) return;

    float acc = (lane < NCLASS) ? logits[(size_t)row * NCLASS + lane] : -INFINITY;

    float m = acc;
    #pragma unroll
    for (int off = 32; off >= 1; off >>= 1)
        m = fmaxf(m, __shfl_xor(m, off));
    float ex = (lane < NCLASS) ? expf(acc - m) : 0.f;
    float s = ex;
    #pragma unroll
    for (int off = 32; off >= 1; off >>= 1)
        s += __shfl_xor(s, off);
    float z1 = acc - (m + logf(s));

    float m2 = z1;
    #pragma unroll
    for (int off = 32; off >= 1; off >>= 1)
        m2 = fmaxf(m2, __shfl_xor(m2, off));
    float ex2 = (lane < NCLASS) ? expf(z1 - m2) : 0.f;
    float s2 = ex2;
    #pragma unroll
    for (int off = 32; off >= 1; off >>= 1)
        s2 += __shfl_xor(s2, off);
    float z2 = z1 - (m2 + logf(s2));

    if (lane < NCLASS)
        Out[(size_t)row * NCLASS + lane] = z2;
}

extern "C" void kernel_launch(void* const* d_in, const int* in_sizes, int n_in,
                              void* d_out, int out_size, void* d_ws, size_t ws_size,
                              hipStream_t stream) {
    const float* feats   = (const float*)d_in[0];
    const int*   e_row   = (const int*)d_in[1];
    const int*   e_col   = (const int*)d_in[2];
    const float* e_vals  = (const float*)d_in[3];
    const float* W1      = (const float*)d_in[4];
    const float* b1      = (const float*)d_in[5];
    const float* W2      = (const float*)d_in[6];
    const float* b2      = (const float*)d_in[7];
    float* out = (float*)d_out;

    // Workspace: y | bufA | bufB  (h1 reuses bufA+bufB after hops;
    // logits reuses y after gemm1 consumed it)
    float* ws   = (float*)d_ws;
    float* y    = ws;
    float* bufA = ws + (size_t)N_NODES * IN_DIM;
    float* bufB = bufA + (size_t)N_NODES * IN_DIM;
    float* h1   = bufA;
    float* logits = y;   // 2M floats, y is dead after gemm1

    // CSR scratch lives in d_out (8 MB; fully overwritten by lsm_kernel at the end).
    // Layout chosen so counts/cursor/row_start are all 16B-aligned for int4 ops.
    int*   csr_col   = (int*)d_out;                    // [0, 800000)
    float* csr_val   = (float*)d_out + N_EDGES;        // [800000, 1600000)
    int*   counts    = (int*)d_out + 2 * N_EDGES;      // [1600000, 1650000)
    int*   cursor    = counts + N_NODES;               // [1650000, 1700000)
    int*   row_start = cursor + N_NODES;               // [1700000, 1750001)
    int*   blockSums = row_start + N_NODES + 4;        // [1750004, 1750053)
    int*   blockOffs = blockSums + 64;                 // [1750068, 1750117)  < 2000000

    const int ELEMS4 = N_NODES * IN_DIM / 4;  // 1.6M
    const int VG = ELEMS4 / 256;              // 6250 exact

    // x = 0.5*feats -> y, bufA; zero counts
    init_kernel<<<VG, 256, 0, stream>>>(feats, y, bufA, counts);

    // Build CSR: count -> hierarchical scan -> scatter
    const int EG = N_EDGES / 256;             // 3125 exact
    count_kernel<<<EG, 256, 0, stream>>>(e_row, counts);
    block_sum_kernel<<<SCAN_NBLK, 256, 0, stream>>>(counts, blockSums);
    block_offset_kernel<<<1, 64, 0, stream>>>(blockSums, blockOffs, row_start);
    local_scan_kernel<<<SCAN_NBLK, 256, 0, stream>>>(counts, blockOffs, row_start, cursor);
    scatter_kernel<<<EG, 256, 0, stream>>>(e_row, e_col, e_vals, cursor, csr_col, csr_val);

    // 3 propagation hops, y-accumulate fused, no atomics, no zeroing
    const int SPMM_BLOCKS = N_NODES / 4;      // 12500 (4 waves/block)
    spmm_csr<<<SPMM_BLOCKS, 256, 0, stream>>>(row_start, csr_col, csr_val, bufA, bufB, y);
    spmm_csr<<<SPMM_BLOCKS, 256, 0, stream>>>(row_start, csr_col, csr_val, bufB, bufA, y);
    spmm_csr<<<SPMM_BLOCKS, 256, 0, stream>>>(row_start, csr_col, csr_val, bufA, bufB, y);

    // GEMM1: h1 = relu((y*0.25) @ W1 + b1)
    dim3 g1((N_NODES + BM - 1) / BM, HID / BN);
    gemm1_kernel<<<g1, 256, 0, stream>>>(y, W1, b1, h1);

    // GEMM2: logits = h1 @ W2 + b2  (into dead y region)
    dim3 g2((N_NODES + BM - 1) / BM, 1);
    gemm2_kernel<<<g2, 256, 0, stream>>>(h1, W2, b2, logits);

    // double log_softmax -> out (overwrites CSR scratch entirely)
    lsm_kernel<<<(N_NODES + 3) / 4, 256, 0, stream>>>(logits, out);
}

// Round 5
// 510.120 us; speedup vs baseline: 8.6819x; 1.0889x over previous
//
#include <hip/hip_runtime.h>
#include <math.h>

#define N_NODES 50000
#define N_EDGES 800000
#define IN_DIM 128
#define HID 256
#define NCLASS 40

#define SCAN_NBLK 49   // ceil(50000 / 1024)

// ---------------- init: y = bufA = 0.5*feats; counts = 0 ----------------
__global__ void init_kernel(const float* __restrict__ feats,
                            float* __restrict__ y,
                            float* __restrict__ bufA,
                            int* __restrict__ counts) {
    int i = blockIdx.x * blockDim.x + threadIdx.x;   // float4 index, 1.6M total
    const float4* f4 = (const float4*)feats;
    float4 v = f4[i];
    v.x *= 0.5f; v.y *= 0.5f; v.z *= 0.5f; v.w *= 0.5f;
    ((float4*)y)[i] = v;
    ((float4*)bufA)[i] = v;
    if (i < N_NODES) counts[i] = 0;
}

// ---------------- CSR build: count ----------------
__global__ void count_kernel(const int* __restrict__ rows,
                             int* __restrict__ counts) {
    int e = blockIdx.x * blockDim.x + threadIdx.x;
    if (e < N_EDGES) atomicAdd(&counts[rows[e]], 1);
}

// ---------------- hierarchical scan, phase 1: per-block sums ----------------
__global__ void block_sum_kernel(const int* __restrict__ counts,
                                 int* __restrict__ blockSums) {
    int t = threadIdx.x;
    int base = blockIdx.x * 1024 + t * 4;
    int s = 0;
    if (base < N_NODES) {
        int4 c = *(const int4*)(counts + base);
        s = c.x + c.y + c.z + c.w;
    }
    #pragma unroll
    for (int off = 32; off >= 1; off >>= 1)
        s += __shfl_xor(s, off);
    __shared__ int wsum[4];
    int lane = t & 63, wid = t >> 6;
    if (lane == 0) wsum[wid] = s;
    __syncthreads();
    if (t == 0)
        blockSums[blockIdx.x] = wsum[0] + wsum[1] + wsum[2] + wsum[3];
}

// ---------------- phase 2: scan the 49 block sums (single wave) ----------------
__global__ void block_offset_kernel(const int* __restrict__ blockSums,
                                    int* __restrict__ blockOffs,
                                    int* __restrict__ row_start) {
    int lane = threadIdx.x;          // 64 threads
    int x = (lane < SCAN_NBLK) ? blockSums[lane] : 0;
    #pragma unroll
    for (int off = 1; off < 64; off <<= 1) {
        int y = __shfl_up(x, off);
        if (lane >= off) x += y;
    }
    int excl = __shfl_up(x, 1);
    if (lane == 0) excl = 0;
    if (lane < SCAN_NBLK) blockOffs[lane] = excl;
    if (lane == SCAN_NBLK - 1) row_start[N_NODES] = x;   // grand total
}

// ---------------- phase 3: local scan + block offset -> row_start, cursor ----------------
__global__ void local_scan_kernel(const int* __restrict__ counts,
                                  const int* __restrict__ blockOffs,
                                  int* __restrict__ row_start,
                                  int* __restrict__ cursor) {
    int t = threadIdx.x;
    int base = blockIdx.x * 1024 + t * 4;
    int4 c = make_int4(0, 0, 0, 0);
    if (base < N_NODES) c = *(const int4*)(counts + base);
    int s0 = c.x, s1 = s0 + c.y, s2 = s1 + c.z, s3 = s2 + c.w;
    int tsum = s3;
    int lane = t & 63, wid = t >> 6;
    int x = tsum;
    #pragma unroll
    for (int off = 1; off < 64; off <<= 1) {
        int y = __shfl_up(x, off);
        if (lane >= off) x += y;
    }
    __shared__ int wsum[4];
    if (lane == 63) wsum[wid] = x;
    __syncthreads();
    int woff = 0;
    for (int i = 0; i < 4; ++i)
        if (i < wid) woff += wsum[i];
    int excl = x - tsum + woff + blockOffs[blockIdx.x];
    if (base < N_NODES) {
        int4 rs = make_int4(excl, excl + s0, excl + s1, excl + s2);
        *(int4*)(row_start + base) = rs;
        *(int4*)(cursor + base) = rs;
    }
}

// ---------------- CSR build: scatter ----------------
__global__ void scatter_kernel(const int* __restrict__ rows,
                               const int* __restrict__ cols,
                               const float* __restrict__ vals,
                               int* __restrict__ cursor,
                               int* __restrict__ csr_col,
                               float* __restrict__ csr_val) {
    int e = blockIdx.x * blockDim.x + threadIdx.x;
    if (e >= N_EDGES) return;
    int pos = atomicAdd(&cursor[rows[e]], 1);
    csr_col[pos] = cols[e];
    csr_val[pos] = vals[e];
}

// ---------------- SpMM (CSR): Hout[r] = sum val*Hin[col]; y[r] += Hout[r]
// Wave per row; half-wave per edge: lane = 32p+q handles dims [4q,4q+4) of edge j+p.
__global__ void spmm_csr(const int* __restrict__ row_start,
                         const int* __restrict__ csr_col,
                         const float* __restrict__ csr_val,
                         const float* __restrict__ Hin,
                         float* __restrict__ Hout,
                         float* __restrict__ y) {
    int wave = (blockIdx.x * blockDim.x + threadIdx.x) >> 6;
    int lane = threadIdx.x & 63;
    if (wave >= N_NODES) return;
    int p = lane >> 5;          // 0 or 1: which edge of the pair
    int q = lane & 31;          // dim group
    int start = row_start[wave];
    int end   = row_start[wave + 1];
    float4 acc = make_float4(0.f, 0.f, 0.f, 0.f);
    for (int base = start; base < end; base += 64) {
        int idx = base + lane;
        int c = 0; float v = 0.f;
        if (idx < end) { c = csr_col[idx]; v = csr_val[idx]; }
        int cnt = min(64, end - base);
        for (int j = 0; j < cnt; j += 2) {
            int src = j + p;                   // <= 63 always; v==0 beyond cnt
            int   cj = __shfl(c, src);
            float vj = __shfl(v, src);
            float4 h = *(const float4*)(Hin + (size_t)cj * IN_DIM + q * 4);
            acc.x += vj * h.x;
            acc.y += vj * h.y;
            acc.z += vj * h.z;
            acc.w += vj * h.w;
        }
    }
    // combine the two half-wave partials (same dims, different edge subsets)
    acc.x += __shfl_xor(acc.x, 32);
    acc.y += __shfl_xor(acc.y, 32);
    acc.z += __shfl_xor(acc.z, 32);
    acc.w += __shfl_xor(acc.w, 32);
    if (p == 0) {
        size_t o = (size_t)wave * IN_DIM + q * 4;
        *(float4*)(Hout + o) = acc;
        float4 yo = *(const float4*)(y + o);
        yo.x += acc.x; yo.y += acc.y; yo.z += acc.z; yo.w += acc.w;
        *(float4*)(y + o) = yo;
    }
}

// ---------------- GEMM1: H1 = relu((y*0.25) @ W1 + b1) ----------------
// 128x128 tile, 8x8 per thread, BK=16, A transposed in LDS (all-b128 reads).
#define BM1 128
#define BN1 128
#define BK1 16
__global__ void gemm1_kernel(const float* __restrict__ Y,
                             const float* __restrict__ W1,
                             const float* __restrict__ bias1,
                             float* __restrict__ H1) {
    __shared__ float As[BK1][BM1 + 4];   // transposed A tile
    __shared__ float Bs[BK1][BN1 + 4];
    int tid = threadIdx.x;               // 256
    int tr = tid >> 4, tc = tid & 15;    // 16x16 thread grid
    int row0 = blockIdx.x * BM1;
    int col0 = blockIdx.y * BN1;
    float acc[8][8] = {};
    for (int k0 = 0; k0 < IN_DIM; k0 += BK1) {   // 8 k-tiles
        // stage A (128x16) transposed: 512 float4, 2 per thread
        #pragma unroll
        for (int i = tid; i < 512; i += 256) {
            int r = i >> 2, c4 = i & 3;
            int gr = row0 + r;
            float4 v = make_float4(0.f, 0.f, 0.f, 0.f);
            if (gr < N_NODES)
                v = *(const float4*)(Y + (size_t)gr * IN_DIM + k0 + c4 * 4);
            As[c4 * 4 + 0][r] = v.x * 0.25f;
            As[c4 * 4 + 1][r] = v.y * 0.25f;
            As[c4 * 4 + 2][r] = v.z * 0.25f;
            As[c4 * 4 + 3][r] = v.w * 0.25f;
        }
        // stage B (16x128): 512 float4, 2 per thread
        #pragma unroll
        for (int i = tid; i < 512; i += 256) {
            int c = i >> 5, n4 = i & 31;
            float4 w = *(const float4*)(W1 + (size_t)(k0 + c) * HID + col0 + n4 * 4);
            *(float4*)&Bs[c][n4 * 4] = w;
        }
        __syncthreads();
        #pragma unroll
        for (int kk = 0; kk < BK1; ++kk) {
            float4 a0 = *(const float4*)&As[kk][tr * 8];
            float4 a1 = *(const float4*)&As[kk][tr * 8 + 4];
            float4 b0 = *(const float4*)&Bs[kk][tc * 8];
            float4 b1v = *(const float4*)&Bs[kk][tc * 8 + 4];
            float a[8] = {a0.x, a0.y, a0.z, a0.w, a1.x, a1.y, a1.z, a1.w};
            float b[8] = {b0.x, b0.y, b0.z, b0.w, b1v.x, b1v.y, b1v.z, b1v.w};
            #pragma unroll
            for (int i = 0; i < 8; ++i)
                #pragma unroll
                for (int j = 0; j < 8; ++j)
                    acc[i][j] += a[i] * b[j];
        }
        __syncthreads();
    }
    float4 bb0 = *(const float4*)(bias1 + col0 + tc * 8);
    float4 bb1 = *(const float4*)(bias1 + col0 + tc * 8 + 4);
    float bb[8] = {bb0.x, bb0.y, bb0.z, bb0.w, bb1.x, bb1.y, bb1.z, bb1.w};
    #pragma unroll
    for (int i = 0; i < 8; ++i) {
        int gr = row0 + tr * 8 + i;
        if (gr >= N_NODES) continue;
        float o[8];
        #pragma unroll
        for (int j = 0; j < 8; ++j) {
            float v = acc[i][j] + bb[j];
            o[j] = v > 0.f ? v : 0.f;
        }
        float* dst = H1 + (size_t)gr * HID + col0 + tc * 8;
        *(float4*)(dst)     = make_float4(o[0], o[1], o[2], o[3]);
        *(float4*)(dst + 4) = make_float4(o[4], o[5], o[6], o[7]);
    }
}

// ---------------- GEMM2: logits = H1 @ W2 + b2  (tiled, NCLASS padded to 64) ----------------
#define BM 64
#define BN 64
#define BK 32
__global__ void gemm2_kernel(const float* __restrict__ H1,
                             const float* __restrict__ W2,
                             const float* __restrict__ b2,
                             float* __restrict__ logits) {
    __shared__ float As[BM][BK + 1];   // 64 x 32
    __shared__ float Bs[BK][BN + 1];   // 32 x 64 (cols >= 40 are zero pad)
    int tid = threadIdx.x;            // 256
    int tr = tid >> 4, tc = tid & 15;
    int row0 = blockIdx.x * BM;
    float acc[4][4] = {};
    for (int k0 = 0; k0 < HID; k0 += BK) {   // 8 k-tiles
        for (int i = tid; i < BM * BK; i += 256) {
            int r = i >> 5, c = i & 31;
            int gr = row0 + r;
            As[r][c] = (gr < N_NODES) ? H1[(size_t)gr * HID + k0 + c] : 0.f;
        }
        for (int i = tid; i < BK * BN; i += 256) {
            int r = i >> 6, c = i & 63;
            Bs[r][c] = (c < NCLASS) ? W2[(size_t)(k0 + r) * NCLASS + c] : 0.f;
        }
        __syncthreads();
        #pragma unroll
        for (int kk = 0; kk < BK; ++kk) {
            float a[4], b[4];
            #pragma unroll
            for (int i = 0; i < 4; ++i) a[i] = As[tr * 4 + i][kk];
            #pragma unroll
            for (int j = 0; j < 4; ++j) b[j] = Bs[kk][tc * 4 + j];
            #pragma unroll
            for (int i = 0; i < 4; ++i)
                #pragma unroll
                for (int j = 0; j < 4; ++j)
                    acc[i][j] += a[i] * b[j];
        }
        __syncthreads();
    }
    #pragma unroll
    for (int i = 0; i < 4; ++i) {
        int gr = row0 + tr * 4 + i;
        if (gr >= N_NODES) continue;
        #pragma unroll
        for (int j = 0; j < 4; ++j) {
            int gc = tc * 4 + j;
            if (gc < NCLASS)
                logits[(size_t)gr * NCLASS + gc] = acc[i][j] + b2[gc];
        }
    }
}

// ---------------- double log_softmax over 40 classes, wave per row ----------------
__global__ void lsm_kernel(const float* __restrict__ logits,
                           float* __restrict__ Out) {
    int wave = threadIdx.x >> 6;
    int lane = threadIdx.x & 63;
    int row = blockIdx.x * 4 + wave;
    if (row >= N_NODES) return;

    float acc = (lane < NCLASS) ? logits[(size_t)row * NCLASS + lane] : -INFINITY;

    float m = acc;
    #pragma unroll
    for (int off = 32; off >= 1; off >>= 1)
        m = fmaxf(m, __shfl_xor(m, off));
    float ex = (lane < NCLASS) ? expf(acc - m) : 0.f;
    float s = ex;
    #pragma unroll
    for (int off = 32; off >= 1; off >>= 1)
        s += __shfl_xor(s, off);
    float z1 = acc - (m + logf(s));

    float m2 = z1;
    #pragma unroll
    for (int off = 32; off >= 1; off >>= 1)
        m2 = fmaxf(m2, __shfl_xor(m2, off));
    float ex2 = (lane < NCLASS) ? expf(z1 - m2) : 0.f;
    float s2 = ex2;
    #pragma unroll
    for (int off = 32; off >= 1; off >>= 1)
        s2 += __shfl_xor(s2, off);
    float z2 = z1 - (m2 + logf(s2));

    if (lane < NCLASS)
        Out[(size_t)row * NCLASS + lane] = z2;
}

extern "C" void kernel_launch(void* const* d_in, const int* in_sizes, int n_in,
                              void* d_out, int out_size, void* d_ws, size_t ws_size,
                              hipStream_t stream) {
    const float* feats   = (const float*)d_in[0];
    const int*   e_row   = (const int*)d_in[1];
    const int*   e_col   = (const int*)d_in[2];
    const float* e_vals  = (const float*)d_in[3];
    const float* W1      = (const float*)d_in[4];
    const float* b1      = (const float*)d_in[5];
    const float* W2      = (const float*)d_in[6];
    const float* b2      = (const float*)d_in[7];
    float* out = (float*)d_out;

    // Workspace: y | bufA | bufB  (h1 reuses bufA+bufB after hops;
    // logits reuses y after gemm1 consumed it)
    float* ws   = (float*)d_ws;
    float* y    = ws;
    float* bufA = ws + (size_t)N_NODES * IN_DIM;
    float* bufB = bufA + (size_t)N_NODES * IN_DIM;
    float* h1   = bufA;
    float* logits = y;   // 2M floats, y is dead after gemm1

    // CSR scratch lives in d_out (8 MB; fully overwritten by lsm_kernel at the end).
    int*   csr_col   = (int*)d_out;                    // [0, 800000)
    float* csr_val   = (float*)d_out + N_EDGES;        // [800000, 1600000)
    int*   counts    = (int*)d_out + 2 * N_EDGES;      // [1600000, 1650000)
    int*   cursor    = counts + N_NODES;               // [1650000, 1700000)
    int*   row_start = cursor + N_NODES;               // [1700000, 1750001)
    int*   blockSums = row_start + N_NODES + 4;        // [1750004, ...)
    int*   blockOffs = blockSums + 64;                 // < 2000000

    const int ELEMS4 = N_NODES * IN_DIM / 4;  // 1.6M
    const int VG = ELEMS4 / 256;              // 6250 exact

    // x = 0.5*feats -> y, bufA; zero counts
    init_kernel<<<VG, 256, 0, stream>>>(feats, y, bufA, counts);

    // Build CSR: count -> hierarchical scan -> scatter
    const int EG = N_EDGES / 256;             // 3125 exact
    count_kernel<<<EG, 256, 0, stream>>>(e_row, counts);
    block_sum_kernel<<<SCAN_NBLK, 256, 0, stream>>>(counts, blockSums);
    block_offset_kernel<<<1, 64, 0, stream>>>(blockSums, blockOffs, row_start);
    local_scan_kernel<<<SCAN_NBLK, 256, 0, stream>>>(counts, blockOffs, row_start, cursor);
    scatter_kernel<<<EG, 256, 0, stream>>>(e_row, e_col, e_vals, cursor, csr_col, csr_val);

    // 3 propagation hops, y-accumulate fused
    const int SPMM_BLOCKS = N_NODES / 4;      // 12500 (4 waves/block)
    spmm_csr<<<SPMM_BLOCKS, 256, 0, stream>>>(row_start, csr_col, csr_val, bufA, bufB, y);
    spmm_csr<<<SPMM_BLOCKS, 256, 0, stream>>>(row_start, csr_col, csr_val, bufB, bufA, y);
    spmm_csr<<<SPMM_BLOCKS, 256, 0, stream>>>(row_start, csr_col, csr_val, bufA, bufB, y);

    // GEMM1: h1 = relu((y*0.25) @ W1 + b1)
    dim3 g1((N_NODES + BM1 - 1) / BM1, HID / BN1);    // (391, 2)
    gemm1_kernel<<<g1, 256, 0, stream>>>(y, W1, b1, h1);

    // GEMM2: logits = h1 @ W2 + b2  (into dead y region)
    dim3 g2((N_NODES + BM - 1) / BM, 1);
    gemm2_kernel<<<g2, 256, 0, stream>>>(h1, W2, b2, logits);

    // double log_softmax -> out (overwrites CSR scratch entirely)
    lsm_kernel<<<(N_NODES + 3) / 4, 256, 0, stream>>>(logits, out);
}

// Round 6
// 475.691 us; speedup vs baseline: 9.3102x; 1.0724x over previous
//
#include <hip/hip_runtime.h>
#include <math.h>

#define N_NODES 50000
#define N_EDGES 800000
#define IN_DIM 128
#define HID 256
#define NCLASS 40

#define SCAN_NBLK 49   // ceil(50000 / 1024)

// ---------------- CSR build: count ----------------
__global__ void count_kernel(const int* __restrict__ rows,
                             int* __restrict__ counts) {
    int e = blockIdx.x * blockDim.x + threadIdx.x;
    if (e < N_EDGES) atomicAdd(&counts[rows[e]], 1);
}

// ---------------- hierarchical scan, phase 1: per-block sums ----------------
__global__ void block_sum_kernel(const int* __restrict__ counts,
                                 int* __restrict__ blockSums) {
    int t = threadIdx.x;
    int base = blockIdx.x * 1024 + t * 4;
    int s = 0;
    if (base < N_NODES) {
        int4 c = *(const int4*)(counts + base);
        s = c.x + c.y + c.z + c.w;
    }
    #pragma unroll
    for (int off = 32; off >= 1; off >>= 1)
        s += __shfl_xor(s, off);
    __shared__ int wsum[4];
    int lane = t & 63, wid = t >> 6;
    if (lane == 0) wsum[wid] = s;
    __syncthreads();
    if (t == 0)
        blockSums[blockIdx.x] = wsum[0] + wsum[1] + wsum[2] + wsum[3];
}

// ---------------- phase 2: scan the 49 block sums (single wave) ----------------
__global__ void block_offset_kernel(const int* __restrict__ blockSums,
                                    int* __restrict__ blockOffs,
                                    int* __restrict__ row_start) {
    int lane = threadIdx.x;          // 64 threads
    int x = (lane < SCAN_NBLK) ? blockSums[lane] : 0;
    #pragma unroll
    for (int off = 1; off < 64; off <<= 1) {
        int y = __shfl_up(x, off);
        if (lane >= off) x += y;
    }
    int excl = __shfl_up(x, 1);
    if (lane == 0) excl = 0;
    if (lane < SCAN_NBLK) blockOffs[lane] = excl;
    if (lane == SCAN_NBLK - 1) row_start[N_NODES] = x;   // grand total
}

// ---------------- phase 3: local scan + block offset -> row_start, cursor ----------------
__global__ void local_scan_kernel(const int* __restrict__ counts,
                                  const int* __restrict__ blockOffs,
                                  int* __restrict__ row_start,
                                  int* __restrict__ cursor) {
    int t = threadIdx.x;
    int base = blockIdx.x * 1024 + t * 4;
    int4 c = make_int4(0, 0, 0, 0);
    if (base < N_NODES) c = *(const int4*)(counts + base);
    int s0 = c.x, s1 = s0 + c.y, s2 = s1 + c.z, s3 = s2 + c.w;
    int tsum = s3;
    int lane = t & 63, wid = t >> 6;
    int x = tsum;
    #pragma unroll
    for (int off = 1; off < 64; off <<= 1) {
        int y = __shfl_up(x, off);
        if (lane >= off) x += y;
    }
    __shared__ int wsum[4];
    if (lane == 63) wsum[wid] = x;
    __syncthreads();
    int woff = 0;
    for (int i = 0; i < 4; ++i)
        if (i < wid) woff += wsum[i];
    int excl = x - tsum + woff + blockOffs[blockIdx.x];
    if (base < N_NODES) {
        int4 rs = make_int4(excl, excl + s0, excl + s1, excl + s2);
        *(int4*)(row_start + base) = rs;
        *(int4*)(cursor + base) = rs;
    }
}

// ---------------- CSR build: scatter (interleaved col+val, single 8B store) ----------------
__global__ void scatter_kernel(const int* __restrict__ rows,
                               const int* __restrict__ cols,
                               const float* __restrict__ vals,
                               int* __restrict__ cursor,
                               int2* __restrict__ csr_cv) {
    int e = blockIdx.x * blockDim.x + threadIdx.x;
    if (e >= N_EDGES) return;
    int pos = atomicAdd(&cursor[rows[e]], 1);
    csr_cv[pos] = make_int2(cols[e], __float_as_int(vals[e]));
}

// ---------------- SpMM (CSR): acc[r] = sum val*Hin[col]
// Wave per row; half-wave per edge: lane = 32p+q handles dims [4q,4q+4) of edge j+p.
// MODE 0: Hout[r] = acc            (hop 2)
// MODE 1: Hout[r] = 0.5*acc        (hop 1, Hin = feats, folds the 0.5 input scale)
// MODE 2: Hout[r] = 0.5*feats[r] + h1[r] + h2[r] + acc   (hop 3, fused y combine)
template <int MODE>
__global__ void spmm_csr(const int* __restrict__ row_start,
                         const int2* __restrict__ csr_cv,
                         const float* __restrict__ Hin,
                         float* __restrict__ Hout,
                         const float* __restrict__ feats,
                         const float* __restrict__ h1,
                         const float* __restrict__ h2) {
    int wave = (blockIdx.x * blockDim.x + threadIdx.x) >> 6;
    int lane = threadIdx.x & 63;
    if (wave >= N_NODES) return;
    int p = lane >> 5;          // 0 or 1: which edge of the pair
    int q = lane & 31;          // dim group
    int start = row_start[wave];
    int end   = row_start[wave + 1];
    float4 acc = make_float4(0.f, 0.f, 0.f, 0.f);
    for (int base = start; base < end; base += 64) {
        int idx = base + lane;
        int c = 0; float v = 0.f;
        if (idx < end) {
            int2 cv = csr_cv[idx];
            c = cv.x;
            v = __int_as_float(cv.y);
        }
        int cnt = min(64, end - base);
        for (int j = 0; j < cnt; j += 2) {
            int src = j + p;                   // <= 63 always; v==0 beyond cnt
            int   cj = __shfl(c, src);
            float vj = __shfl(v, src);
            float4 h = *(const float4*)(Hin + (size_t)cj * IN_DIM + q * 4);
            acc.x += vj * h.x;
            acc.y += vj * h.y;
            acc.z += vj * h.z;
            acc.w += vj * h.w;
        }
    }
    // combine the two half-wave partials
    acc.x += __shfl_xor(acc.x, 32);
    acc.y += __shfl_xor(acc.y, 32);
    acc.z += __shfl_xor(acc.z, 32);
    acc.w += __shfl_xor(acc.w, 32);
    if (p == 0) {
        size_t o = (size_t)wave * IN_DIM + q * 4;
        if (MODE == 1) {
            acc.x *= 0.5f; acc.y *= 0.5f; acc.z *= 0.5f; acc.w *= 0.5f;
        } else if (MODE == 2) {
            float4 f = *(const float4*)(feats + o);
            float4 a = *(const float4*)(h1 + o);
            float4 b = *(const float4*)(h2 + o);
            acc.x += 0.5f * f.x + a.x + b.x;
            acc.y += 0.5f * f.y + a.y + b.y;
            acc.z += 0.5f * f.z + a.z + b.z;
            acc.w += 0.5f * f.w + a.w + b.w;
        }
        *(float4*)(Hout + o) = acc;
    }
}

// ---------------- GEMM1: H1 = relu((y*0.25) @ W1 + b1) ----------------
// 128x128 tile, 8x8 per thread, BK=16, A transposed in LDS (all-b128 reads).
#define BM1 128
#define BN1 128
#define BK1 16
__global__ void gemm1_kernel(const float* __restrict__ Y,
                             const float* __restrict__ W1,
                             const float* __restrict__ bias1,
                             float* __restrict__ H1) {
    __shared__ float As[BK1][BM1 + 4];   // transposed A tile
    __shared__ float Bs[BK1][BN1 + 4];
    int tid = threadIdx.x;               // 256
    int tr = tid >> 4, tc = tid & 15;    // 16x16 thread grid
    int row0 = blockIdx.x * BM1;
    int col0 = blockIdx.y * BN1;
    float acc[8][8] = {};
    for (int k0 = 0; k0 < IN_DIM; k0 += BK1) {   // 8 k-tiles
        #pragma unroll
        for (int i = tid; i < 512; i += 256) {
            int r = i >> 2, c4 = i & 3;
            int gr = row0 + r;
            float4 v = make_float4(0.f, 0.f, 0.f, 0.f);
            if (gr < N_NODES)
                v = *(const float4*)(Y + (size_t)gr * IN_DIM + k0 + c4 * 4);
            As[c4 * 4 + 0][r] = v.x * 0.25f;
            As[c4 * 4 + 1][r] = v.y * 0.25f;
            As[c4 * 4 + 2][r] = v.z * 0.25f;
            As[c4 * 4 + 3][r] = v.w * 0.25f;
        }
        #pragma unroll
        for (int i = tid; i < 512; i += 256) {
            int c = i >> 5, n4 = i & 31;
            float4 w = *(const float4*)(W1 + (size_t)(k0 + c) * HID + col0 + n4 * 4);
            *(float4*)&Bs[c][n4 * 4] = w;
        }
        __syncthreads();
        #pragma unroll
        for (int kk = 0; kk < BK1; ++kk) {
            float4 a0 = *(const float4*)&As[kk][tr * 8];
            float4 a1 = *(const float4*)&As[kk][tr * 8 + 4];
            float4 b0 = *(const float4*)&Bs[kk][tc * 8];
            float4 b1v = *(const float4*)&Bs[kk][tc * 8 + 4];
            float a[8] = {a0.x, a0.y, a0.z, a0.w, a1.x, a1.y, a1.z, a1.w};
            float b[8] = {b0.x, b0.y, b0.z, b0.w, b1v.x, b1v.y, b1v.z, b1v.w};
            #pragma unroll
            for (int i = 0; i < 8; ++i)
                #pragma unroll
                for (int j = 0; j < 8; ++j)
                    acc[i][j] += a[i] * b[j];
        }
        __syncthreads();
    }
    float4 bb0 = *(const float4*)(bias1 + col0 + tc * 8);
    float4 bb1 = *(const float4*)(bias1 + col0 + tc * 8 + 4);
    float bb[8] = {bb0.x, bb0.y, bb0.z, bb0.w, bb1.x, bb1.y, bb1.z, bb1.w};
    #pragma unroll
    for (int i = 0; i < 8; ++i) {
        int gr = row0 + tr * 8 + i;
        if (gr >= N_NODES) continue;
        float o[8];
        #pragma unroll
        for (int j = 0; j < 8; ++j) {
            float v = acc[i][j] + bb[j];
            o[j] = v > 0.f ? v : 0.f;
        }
        float* dst = H1 + (size_t)gr * HID + col0 + tc * 8;
        *(float4*)(dst)     = make_float4(o[0], o[1], o[2], o[3]);
        *(float4*)(dst + 4) = make_float4(o[4], o[5], o[6], o[7]);
    }
}

// ---------------- GEMM2: logits = H1 @ W2 + b2  (tiled, NCLASS padded to 64) ----------------
#define BM 64
#define BN 64
#define BK 32
__global__ void gemm2_kernel(const float* __restrict__ H1,
                             const float* __restrict__ W2,
                             const float* __restrict__ b2,
                             float* __restrict__ logits) {
    __shared__ float As[BM][BK + 1];   // 64 x 32
    __shared__ float Bs[BK][BN + 1];   // 32 x 64 (cols >= 40 are zero pad)
    int tid = threadIdx.x;            // 256
    int tr = tid >> 4, tc = tid & 15;
    int row0 = blockIdx.x * BM;
    float acc[4][4] = {};
    for (int k0 = 0; k0 < HID; k0 += BK) {   // 8 k-tiles
        for (int i = tid; i < BM * BK; i += 256) {
            int r = i >> 5, c = i & 31;
            int gr = row0 + r;
            As[r][c] = (gr < N_NODES) ? H1[(size_t)gr * HID + k0 + c] : 0.f;
        }
        for (int i = tid; i < BK * BN; i += 256) {
            int r = i >> 6, c = i & 63;
            Bs[r][c] = (c < NCLASS) ? W2[(size_t)(k0 + r) * NCLASS + c] : 0.f;
        }
        __syncthreads();
        #pragma unroll
        for (int kk = 0; kk < BK; ++kk) {
            float a[4], b[4];
            #pragma unroll
            for (int i = 0; i < 4; ++i) a[i] = As[tr * 4 + i][kk];
            #pragma unroll
            for (int j = 0; j < 4; ++j) b[j] = Bs[kk][tc * 4 + j];
            #pragma unroll
            for (int i = 0; i < 4; ++i)
                #pragma unroll
                for (int j = 0; j < 4; ++j)
                    acc[i][j] += a[i] * b[j];
        }
        __syncthreads();
    }
    #pragma unroll
    for (int i = 0; i < 4; ++i) {
        int gr = row0 + tr * 4 + i;
        if (gr >= N_NODES) continue;
        #pragma unroll
        for (int j = 0; j < 4; ++j) {
            int gc = tc * 4 + j;
            if (gc < NCLASS)
                logits[(size_t)gr * NCLASS + gc] = acc[i][j] + b2[gc];
        }
    }
}

// ---------------- double log_softmax over 40 classes, wave per row ----------------
__global__ void lsm_kernel(const float* __restrict__ logits,
                           float* __restrict__ Out) {
    int wave = threadIdx.x >> 6;
    int lane = threadIdx.x & 63;
    int row = blockIdx.x * 4 + wave;
    if (row >= N_NODES) return;

    float acc = (lane < NCLASS) ? logits[(size_t)row * NCLASS + lane] : -INFINITY;

    float m = acc;
    #pragma unroll
    for (int off = 32; off >= 1; off >>= 1)
        m = fmaxf(m, __shfl_xor(m, off));
    float ex = (lane < NCLASS) ? expf(acc - m) : 0.f;
    float s = ex;
    #pragma unroll
    for (int off = 32; off >= 1; off >>= 1)
        s += __shfl_xor(s, off);
    float z1 = acc - (m + logf(s));

    float m2 = z1;
    #pragma unroll
    for (int off = 32; off >= 1; off >>= 1)
        m2 = fmaxf(m2, __shfl_xor(m2, off));
    float ex2 = (lane < NCLASS) ? expf(z1 - m2) : 0.f;
    float s2 = ex2;
    #pragma unroll
    for (int off = 32; off >= 1; off >>= 1)
        s2 += __shfl_xor(s2, off);
    float z2 = z1 - (m2 + logf(s2));

    if (lane < NCLASS)
        Out[(size_t)row * NCLASS + lane] = z2;
}

extern "C" void kernel_launch(void* const* d_in, const int* in_sizes, int n_in,
                              void* d_out, int out_size, void* d_ws, size_t ws_size,
                              hipStream_t stream) {
    const float* feats   = (const float*)d_in[0];
    const int*   e_row   = (const int*)d_in[1];
    const int*   e_col   = (const int*)d_in[2];
    const float* e_vals  = (const float*)d_in[3];
    const float* W1      = (const float*)d_in[4];
    const float* b1      = (const float*)d_in[5];
    const float* W2      = (const float*)d_in[6];
    const float* b2      = (const float*)d_in[7];
    float* out = (float*)d_out;

    // Workspace (19.2M floats proven): h1 | h2 | y
    // After hop3, gemm1 reads y only -> MLP hidden reuses [h1,h2) = 12.8M floats;
    // logits reuses y after gemm1.
    float* ws    = (float*)d_ws;
    float* h1buf = ws;                                   // [0, 6.4M)
    float* h2buf = ws + (size_t)N_NODES * IN_DIM;        // [6.4M, 12.8M)
    float* ybuf  = h2buf + (size_t)N_NODES * IN_DIM;     // [12.8M, 19.2M)
    float* hid   = ws;                                   // 12.8M floats (h1+h2, dead)
    float* logits = ybuf;                                // 2M floats (y dead after gemm1)

    // CSR scratch in d_out (8 MB; fully overwritten by lsm_kernel at the end).
    int2*  csr_cv    = (int2*)d_out;                     // [0, 1.6M ints) interleaved
    int*   counts    = (int*)d_out + 2 * N_EDGES;        // [1600000, 1650000)
    int*   cursor    = counts + N_NODES;                 // [1650000, 1700000)
    int*   row_start = cursor + N_NODES;                 // [1700000, 1750001)
    int*   blockSums = row_start + N_NODES + 4;
    int*   blockOffs = blockSums + 64;                   // < 2000000

    // zero counts (200 KB)
    hipMemsetAsync(counts, 0, N_NODES * sizeof(int), stream);

    // Build CSR: count -> hierarchical scan -> scatter
    const int EG = N_EDGES / 256;             // 3125 exact
    count_kernel<<<EG, 256, 0, stream>>>(e_row, counts);
    block_sum_kernel<<<SCAN_NBLK, 256, 0, stream>>>(counts, blockSums);
    block_offset_kernel<<<1, 64, 0, stream>>>(blockSums, blockOffs, row_start);
    local_scan_kernel<<<SCAN_NBLK, 256, 0, stream>>>(counts, blockOffs, row_start, cursor);
    scatter_kernel<<<EG, 256, 0, stream>>>(e_row, e_col, e_vals, cursor, csr_cv);

    // 3 propagation hops (no y RMW; hop1 folds the 0.5 scale, hop3 fuses the combine)
    const int SPMM_BLOCKS = N_NODES / 4;      // 12500 (4 waves/block)
    spmm_csr<1><<<SPMM_BLOCKS, 256, 0, stream>>>(row_start, csr_cv, feats, h1buf,
                                                 nullptr, nullptr, nullptr);
    spmm_csr<0><<<SPMM_BLOCKS, 256, 0, stream>>>(row_start, csr_cv, h1buf, h2buf,
                                                 nullptr, nullptr, nullptr);
    spmm_csr<2><<<SPMM_BLOCKS, 256, 0, stream>>>(row_start, csr_cv, h2buf, ybuf,
                                                 feats, h1buf, h2buf);

    // GEMM1: hid = relu((y*0.25) @ W1 + b1)
    dim3 g1((N_NODES + BM1 - 1) / BM1, HID / BN1);    // (391, 2)
    gemm1_kernel<<<g1, 256, 0, stream>>>(ybuf, W1, b1, hid);

    // GEMM2: logits = hid @ W2 + b2  (into dead y region)
    dim3 g2((N_NODES + BM - 1) / BM, 1);
    gemm2_kernel<<<g2, 256, 0, stream>>>(hid, W2, b2, logits);

    // double log_softmax -> out (overwrites CSR scratch entirely)
    lsm_kernel<<<(N_NODES + 3) / 4, 256, 0, stream>>>(logits, out);
}

// Round 7
// 427.363 us; speedup vs baseline: 10.3630x; 1.1131x over previous
//
#include <hip/hip_runtime.h>
#include <math.h>

#define N_NODES 50000
#define N_EDGES 800000
#define IN_DIM 128
#define HID 256
#define NCLASS 40

#define SCAN_NBLK 49   // ceil(50000 / 1024)

// ---------- bf16 helpers (RNE pack, cheap unpack) ----------
__device__ inline unsigned bf16pair(float a, float b) {
    unsigned ua = __float_as_uint(a), ub = __float_as_uint(b);
    ua = (ua + 0x7fffu + ((ua >> 16) & 1u)) >> 16;
    ub = (ub + 0x7fffu + ((ub >> 16) & 1u)) >> 16;
    return ua | (ub << 16);
}
__device__ inline float bf_lo(unsigned u) { return __uint_as_float(u << 16); }
__device__ inline float bf_hi(unsigned u) { return __uint_as_float(u & 0xffff0000u); }

// ---------------- convert feats -> bf16 (packed) ----------------
__global__ void to_bf16_kernel(const float4* __restrict__ f4,
                               uint2* __restrict__ o) {
    int i = blockIdx.x * blockDim.x + threadIdx.x;   // 1.6M float4s
    float4 v = f4[i];
    o[i] = make_uint2(bf16pair(v.x, v.y), bf16pair(v.z, v.w));
}

// ---------------- CSR build: count ----------------
__global__ void count_kernel(const int* __restrict__ rows,
                             int* __restrict__ counts) {
    int e = blockIdx.x * blockDim.x + threadIdx.x;
    if (e < N_EDGES) atomicAdd(&counts[rows[e]], 1);
}

// ---------------- hierarchical scan, phase 1: per-block sums ----------------
__global__ void block_sum_kernel(const int* __restrict__ counts,
                                 int* __restrict__ blockSums) {
    int t = threadIdx.x;
    int base = blockIdx.x * 1024 + t * 4;
    int s = 0;
    if (base < N_NODES) {
        int4 c = *(const int4*)(counts + base);
        s = c.x + c.y + c.z + c.w;
    }
    #pragma unroll
    for (int off = 32; off >= 1; off >>= 1)
        s += __shfl_xor(s, off);
    __shared__ int wsum[4];
    int lane = t & 63, wid = t >> 6;
    if (lane == 0) wsum[wid] = s;
    __syncthreads();
    if (t == 0)
        blockSums[blockIdx.x] = wsum[0] + wsum[1] + wsum[2] + wsum[3];
}

// ---------------- phase 2: scan the 49 block sums (single wave) ----------------
__global__ void block_offset_kernel(const int* __restrict__ blockSums,
                                    int* __restrict__ blockOffs,
                                    int* __restrict__ row_start) {
    int lane = threadIdx.x;          // 64 threads
    int x = (lane < SCAN_NBLK) ? blockSums[lane] : 0;
    #pragma unroll
    for (int off = 1; off < 64; off <<= 1) {
        int y = __shfl_up(x, off);
        if (lane >= off) x += y;
    }
    int excl = __shfl_up(x, 1);
    if (lane == 0) excl = 0;
    if (lane < SCAN_NBLK) blockOffs[lane] = excl;
    if (lane == SCAN_NBLK - 1) row_start[N_NODES] = x;   // grand total
}

// ---------------- phase 3: local scan + block offset -> row_start, cursor ----------------
__global__ void local_scan_kernel(const int* __restrict__ counts,
                                  const int* __restrict__ blockOffs,
                                  int* __restrict__ row_start,
                                  int* __restrict__ cursor) {
    int t = threadIdx.x;
    int base = blockIdx.x * 1024 + t * 4;
    int4 c = make_int4(0, 0, 0, 0);
    if (base < N_NODES) c = *(const int4*)(counts + base);
    int s0 = c.x, s1 = s0 + c.y, s2 = s1 + c.z, s3 = s2 + c.w;
    int tsum = s3;
    int lane = t & 63, wid = t >> 6;
    int x = tsum;
    #pragma unroll
    for (int off = 1; off < 64; off <<= 1) {
        int y = __shfl_up(x, off);
        if (lane >= off) x += y;
    }
    __shared__ int wsum[4];
    if (lane == 63) wsum[wid] = x;
    __syncthreads();
    int woff = 0;
    for (int i = 0; i < 4; ++i)
        if (i < wid) woff += wsum[i];
    int excl = x - tsum + woff + blockOffs[blockIdx.x];
    if (base < N_NODES) {
        int4 rs = make_int4(excl, excl + s0, excl + s1, excl + s2);
        *(int4*)(row_start + base) = rs;
        *(int4*)(cursor + base) = rs;
    }
}

// ---------------- CSR build: scatter (interleaved col+val, single 8B store) ----------------
__global__ void scatter_kernel(const int* __restrict__ rows,
                               const int* __restrict__ cols,
                               const float* __restrict__ vals,
                               int* __restrict__ cursor,
                               int2* __restrict__ csr_cv) {
    int e = blockIdx.x * blockDim.x + threadIdx.x;
    if (e >= N_EDGES) return;
    int pos = atomicAdd(&cursor[rows[e]], 1);
    csr_cv[pos] = make_int2(cols[e], __float_as_int(vals[e]));
}

// ---------------- SpMM (CSR, bf16 gather, fp32 accumulate) ----------------
// Wave per row; half-wave per edge: lane = 32p+q handles dims [4q,4q+4) of edge j+p.
// MODE 0: Hout_b[r] = bf16(acc)                         (hop 2)
// MODE 1: Hout_b[r] = bf16(0.5*acc)                     (hop 1, folds input scale)
// MODE 2: Yout[r]   = 0.5*feats[r] + h1[r] + h2[r] + acc (hop 3, fp32 combine)
template <int MODE>
__global__ void spmm_csr(const int* __restrict__ row_start,
                         const int2* __restrict__ csr_cv,
                         const uint2* __restrict__ Hin_b,
                         uint2* __restrict__ Hout_b,
                         float* __restrict__ Yout,
                         const float* __restrict__ feats,
                         const uint2* __restrict__ h1b,
                         const uint2* __restrict__ h2b) {
    int wave = (blockIdx.x * blockDim.x + threadIdx.x) >> 6;
    int lane = threadIdx.x & 63;
    if (wave >= N_NODES) return;
    int p = lane >> 5;          // which edge of the pair
    int q = lane & 31;          // dim group (4 dims)
    int start = row_start[wave];
    int end   = row_start[wave + 1];
    float4 acc = make_float4(0.f, 0.f, 0.f, 0.f);
    for (int base = start; base < end; base += 64) {
        int idx = base + lane;
        int c = 0; float v = 0.f;
        if (idx < end) {
            int2 cv = csr_cv[idx];
            c = cv.x;
            v = __int_as_float(cv.y);
        }
        int cnt = min(64, end - base);
        for (int j = 0; j < cnt; j += 2) {
            int src = j + p;                   // v==0 beyond cnt
            int   cj = __shfl(c, src);
            float vj = __shfl(v, src);
            uint2 h = Hin_b[(size_t)cj * 32 + q];   // 4 bf16 = 8 B
            acc.x += vj * bf_lo(h.x);
            acc.y += vj * bf_hi(h.x);
            acc.z += vj * bf_lo(h.y);
            acc.w += vj * bf_hi(h.y);
        }
    }
    // combine the two half-wave partials
    acc.x += __shfl_xor(acc.x, 32);
    acc.y += __shfl_xor(acc.y, 32);
    acc.z += __shfl_xor(acc.z, 32);
    acc.w += __shfl_xor(acc.w, 32);
    if (p == 0) {
        size_t o32 = (size_t)wave * 32 + q;
        if (MODE == 1) {
            acc.x *= 0.5f; acc.y *= 0.5f; acc.z *= 0.5f; acc.w *= 0.5f;
            Hout_b[o32] = make_uint2(bf16pair(acc.x, acc.y), bf16pair(acc.z, acc.w));
        } else if (MODE == 0) {
            Hout_b[o32] = make_uint2(bf16pair(acc.x, acc.y), bf16pair(acc.z, acc.w));
        } else {
            size_t o = (size_t)wave * IN_DIM + q * 4;
            float4 f = *(const float4*)(feats + o);
            uint2 a = h1b[o32];
            uint2 b = h2b[o32];
            acc.x += 0.5f * f.x + bf_lo(a.x) + bf_lo(b.x);
            acc.y += 0.5f * f.y + bf_hi(a.x) + bf_hi(b.x);
            acc.z += 0.5f * f.z + bf_lo(a.y) + bf_lo(b.y);
            acc.w += 0.5f * f.w + bf_hi(a.y) + bf_hi(b.y);
            *(float4*)(Yout + o) = acc;
        }
    }
}

// ---------------- GEMM1: H1 = relu((y*0.25) @ W1 + b1) ----------------
// 128x128 tile, 8x8 per thread, BK=16, A transposed in LDS (all-b128 reads).
#define BM1 128
#define BN1 128
#define BK1 16
__global__ void gemm1_kernel(const float* __restrict__ Y,
                             const float* __restrict__ W1,
                             const float* __restrict__ bias1,
                             float* __restrict__ H1) {
    __shared__ float As[BK1][BM1 + 4];   // transposed A tile
    __shared__ float Bs[BK1][BN1 + 4];
    int tid = threadIdx.x;               // 256
    int tr = tid >> 4, tc = tid & 15;    // 16x16 thread grid
    int row0 = blockIdx.x * BM1;
    int col0 = blockIdx.y * BN1;
    float acc[8][8] = {};
    for (int k0 = 0; k0 < IN_DIM; k0 += BK1) {   // 8 k-tiles
        #pragma unroll
        for (int i = tid; i < 512; i += 256) {
            int r = i >> 2, c4 = i & 3;
            int gr = row0 + r;
            float4 v = make_float4(0.f, 0.f, 0.f, 0.f);
            if (gr < N_NODES)
                v = *(const float4*)(Y + (size_t)gr * IN_DIM + k0 + c4 * 4);
            As[c4 * 4 + 0][r] = v.x * 0.25f;
            As[c4 * 4 + 1][r] = v.y * 0.25f;
            As[c4 * 4 + 2][r] = v.z * 0.25f;
            As[c4 * 4 + 3][r] = v.w * 0.25f;
        }
        #pragma unroll
        for (int i = tid; i < 512; i += 256) {
            int c = i >> 5, n4 = i & 31;
            float4 w = *(const float4*)(W1 + (size_t)(k0 + c) * HID + col0 + n4 * 4);
            *(float4*)&Bs[c][n4 * 4] = w;
        }
        __syncthreads();
        #pragma unroll
        for (int kk = 0; kk < BK1; ++kk) {
            float4 a0 = *(const float4*)&As[kk][tr * 8];
            float4 a1 = *(const float4*)&As[kk][tr * 8 + 4];
            float4 b0 = *(const float4*)&Bs[kk][tc * 8];
            float4 b1v = *(const float4*)&Bs[kk][tc * 8 + 4];
            float a[8] = {a0.x, a0.y, a0.z, a0.w, a1.x, a1.y, a1.z, a1.w};
            float b[8] = {b0.x, b0.y, b0.z, b0.w, b1v.x, b1v.y, b1v.z, b1v.w};
            #pragma unroll
            for (int i = 0; i < 8; ++i)
                #pragma unroll
                for (int j = 0; j < 8; ++j)
                    acc[i][j] += a[i] * b[j];
        }
        __syncthreads();
    }
    float4 bb0 = *(const float4*)(bias1 + col0 + tc * 8);
    float4 bb1 = *(const float4*)(bias1 + col0 + tc * 8 + 4);
    float bb[8] = {bb0.x, bb0.y, bb0.z, bb0.w, bb1.x, bb1.y, bb1.z, bb1.w};
    #pragma unroll
    for (int i = 0; i < 8; ++i) {
        int gr = row0 + tr * 8 + i;
        if (gr >= N_NODES) continue;
        float o[8];
        #pragma unroll
        for (int j = 0; j < 8; ++j) {
            float v = acc[i][j] + bb[j];
            o[j] = v > 0.f ? v : 0.f;
        }
        float* dst = H1 + (size_t)gr * HID + col0 + tc * 8;
        *(float4*)(dst)     = make_float4(o[0], o[1], o[2], o[3]);
        *(float4*)(dst + 4) = make_float4(o[4], o[5], o[6], o[7]);
    }
}

// ---------------- GEMM2: logits = H1 @ W2 + b2  (tiled, NCLASS padded to 64) ----------------
#define BM 64
#define BN 64
#define BK 32
__global__ void gemm2_kernel(const float* __restrict__ H1,
                             const float* __restrict__ W2,
                             const float* __restrict__ b2,
                             float* __restrict__ logits) {
    __shared__ float As[BM][BK + 1];
    __shared__ float Bs[BK][BN + 1];
    int tid = threadIdx.x;            // 256
    int tr = tid >> 4, tc = tid & 15;
    int row0 = blockIdx.x * BM;
    float acc[4][4] = {};
    for (int k0 = 0; k0 < HID; k0 += BK) {   // 8 k-tiles
        for (int i = tid; i < BM * BK; i += 256) {
            int r = i >> 5, c = i & 31;
            int gr = row0 + r;
            As[r][c] = (gr < N_NODES) ? H1[(size_t)gr * HID + k0 + c] : 0.f;
        }
        for (int i = tid; i < BK * BN; i += 256) {
            int r = i >> 6, c = i & 63;
            Bs[r][c] = (c < NCLASS) ? W2[(size_t)(k0 + r) * NCLASS + c] : 0.f;
        }
        __syncthreads();
        #pragma unroll
        for (int kk = 0; kk < BK; ++kk) {
            float a[4], b[4];
            #pragma unroll
            for (int i = 0; i < 4; ++i) a[i] = As[tr * 4 + i][kk];
            #pragma unroll
            for (int j = 0; j < 4; ++j) b[j] = Bs[kk][tc * 4 + j];
            #pragma unroll
            for (int i = 0; i < 4; ++i)
                #pragma unroll
                for (int j = 0; j < 4; ++j)
                    acc[i][j] += a[i] * b[j];
        }
        __syncthreads();
    }
    #pragma unroll
    for (int i = 0; i < 4; ++i) {
        int gr = row0 + tr * 4 + i;
        if (gr >= N_NODES) continue;
        #pragma unroll
        for (int j = 0; j < 4; ++j) {
            int gc = tc * 4 + j;
            if (gc < NCLASS)
                logits[(size_t)gr * NCLASS + gc] = acc[i][j] + b2[gc];
        }
    }
}

// ---------------- double log_softmax over 40 classes, wave per row ----------------
__global__ void lsm_kernel(const float* __restrict__ logits,
                           float* __restrict__ Out) {
    int wave = threadIdx.x >> 6;
    int lane = threadIdx.x & 63;
    int row = blockIdx.x * 4 + wave;
    if (row >= N_NODES) return;

    float acc = (lane < NCLASS) ? logits[(size_t)row * NCLASS + lane] : -INFINITY;

    float m = acc;
    #pragma unroll
    for (int off = 32; off >= 1; off >>= 1)
        m = fmaxf(m, __shfl_xor(m, off));
    float ex = (lane < NCLASS) ? expf(acc - m) : 0.f;
    float s = ex;
    #pragma unroll
    for (int off = 32; off >= 1; off >>= 1)
        s += __shfl_xor(s, off);
    float z1 = acc - (m + logf(s));

    float m2 = z1;
    #pragma unroll
    for (int off = 32; off >= 1; off >>= 1)
        m2 = fmaxf(m2, __shfl_xor(m2, off));
    float ex2 = (lane < NCLASS) ? expf(z1 - m2) : 0.f;
    float s2 = ex2;
    #pragma unroll
    for (int off = 32; off >= 1; off >>= 1)
        s2 += __shfl_xor(s2, off);
    float z2 = z1 - (m2 + logf(s2));

    if (lane < NCLASS)
        Out[(size_t)row * NCLASS + lane] = z2;
}

extern "C" void kernel_launch(void* const* d_in, const int* in_sizes, int n_in,
                              void* d_out, int out_size, void* d_ws, size_t ws_size,
                              hipStream_t stream) {
    const float* feats   = (const float*)d_in[0];
    const int*   e_row   = (const int*)d_in[1];
    const int*   e_col   = (const int*)d_in[2];
    const float* e_vals  = (const float*)d_in[3];
    const float* W1      = (const float*)d_in[4];
    const float* b1      = (const float*)d_in[5];
    const float* W2      = (const float*)d_in[6];
    const float* b2      = (const float*)d_in[7];
    float* out = (float*)d_out;

    // Workspace (19.2M floats proven):
    //   y    : [0, 6.4M)            fp32 MLP input
    //   fb16 : [6.4M, 9.6M)         feats in bf16 (3.2M float-slots)
    //   h1b  : [9.6M, 12.8M)        hop1 out, bf16
    //   h2b  : [12.8M, 16M)         hop2 out, bf16
    //   hid  : [6.4M, 19.2M)        gemm1 out (bf16 bufs dead by then)
    //   logits: [0, 2M)             (y dead after gemm1)
    float* ws    = (float*)d_ws;
    float* ybuf  = ws;
    uint2* fb16  = (uint2*)(ws + (size_t)N_NODES * IN_DIM);
    uint2* h1b   = (uint2*)(ws + (size_t)N_NODES * IN_DIM * 3 / 2);
    uint2* h2b   = (uint2*)(ws + (size_t)N_NODES * IN_DIM * 2);
    float* hid   = ws + (size_t)N_NODES * IN_DIM;
    float* logits = ws;

    // CSR scratch in d_out (8 MB; fully overwritten by lsm_kernel at the end).
    int2*  csr_cv    = (int2*)d_out;                     // interleaved (col,val)
    int*   counts    = (int*)d_out + 2 * N_EDGES;        // [1600000, 1650000)
    int*   cursor    = counts + N_NODES;                 // [1650000, 1700000)
    int*   row_start = cursor + N_NODES;                 // [1700000, 1750001)
    int*   blockSums = row_start + N_NODES + 4;
    int*   blockOffs = blockSums + 64;                   // < 2000000

    // zero counts (200 KB)
    hipMemsetAsync(counts, 0, N_NODES * sizeof(int), stream);

    // feats -> bf16 (packed)
    const int ELEMS4 = N_NODES * IN_DIM / 4;  // 1.6M float4s
    to_bf16_kernel<<<ELEMS4 / 256, 256, 0, stream>>>((const float4*)feats, fb16);

    // Build CSR: count -> hierarchical scan -> scatter
    const int EG = N_EDGES / 256;             // 3125 exact
    count_kernel<<<EG, 256, 0, stream>>>(e_row, counts);
    block_sum_kernel<<<SCAN_NBLK, 256, 0, stream>>>(counts, blockSums);
    block_offset_kernel<<<1, 64, 0, stream>>>(blockSums, blockOffs, row_start);
    local_scan_kernel<<<SCAN_NBLK, 256, 0, stream>>>(counts, blockOffs, row_start, cursor);
    scatter_kernel<<<EG, 256, 0, stream>>>(e_row, e_col, e_vals, cursor, csr_cv);

    // 3 propagation hops (bf16 gather, fp32 accumulate; hop3 fuses fp32 combine)
    const int SPMM_BLOCKS = N_NODES / 4;      // 12500 (4 waves/block)
    spmm_csr<1><<<SPMM_BLOCKS, 256, 0, stream>>>(row_start, csr_cv, fb16, h1b,
                                                 nullptr, nullptr, nullptr, nullptr);
    spmm_csr<0><<<SPMM_BLOCKS, 256, 0, stream>>>(row_start, csr_cv, h1b, h2b,
                                                 nullptr, nullptr, nullptr, nullptr);
    spmm_csr<2><<<SPMM_BLOCKS, 256, 0, stream>>>(row_start, csr_cv, h2b, nullptr,
                                                 ybuf, feats, h1b, h2b);

    // GEMM1: hid = relu((y*0.25) @ W1 + b1)
    dim3 g1((N_NODES + BM1 - 1) / BM1, HID / BN1);    // (391, 2)
    gemm1_kernel<<<g1, 256, 0, stream>>>(ybuf, W1, b1, hid);

    // GEMM2: logits = hid @ W2 + b2  (into dead y region)
    dim3 g2((N_NODES + BM - 1) / BM, 1);
    gemm2_kernel<<<g2, 256, 0, stream>>>(hid, W2, b2, logits);

    // double log_softmax -> out (overwrites CSR scratch entirely)
    lsm_kernel<<<(N_NODES + 3) / 4, 256, 0, stream>>>(logits, out);
}